// Round 8
// baseline (642.587 us; speedup 1.0000x reference)
//
#include <hip/hip_runtime.h>
#include <cstdint>
#include <cstddef>

#define NEG_SLOPE 0.2f

__device__ __forceinline__ float leakyf(float x) { return x > 0.f ? x : NEG_SLOPE * x; }
__device__ __forceinline__ float fast_tanh(float x) {
    float e = __expf(2.f * x);
    return 1.f - 2.f / (e + 1.f);
}

// ---------------- projection (x@W+b) + per-head attention dots ----------------
// block 256 = 8 row-groups x 32 col-threads; 32 rows/block, thread = 4 rows x 4 contiguous cols.
// W K-chunks double-buffered through REGISTERS: next chunk's L2 loads issue before the
// current chunk's compute, so staging latency hides under FMAs.
__global__ __launch_bounds__(256) void proj_kernel(
    const float* __restrict__ x, const float* __restrict__ W, const float* __restrict__ bias,
    float* __restrict__ hout, int N,
    const float* __restrict__ att0, float* __restrict__ e0,
    const float* __restrict__ att1, float* __restrict__ e1,
    const float* __restrict__ att2, float* __restrict__ e2)
{
    __shared__ float xlds[32 * 128];  // 16 KB: x tile
    __shared__ float wlds[32 * 128];  // 16 KB: W K-chunk
    const int t = threadIdx.x;
    const int row0 = blockIdx.x * 32;
    #pragma unroll
    for (int p = 0; p < 4; ++p) {
        int idx = t + 256 * p;
        int r = idx >> 5;
        int c4 = idx & 31;
        float4 v = make_float4(0.f, 0.f, 0.f, 0.f);
        if (row0 + r < N) v = *(const float4*)(x + (size_t)(row0 + r) * 128 + c4 * 4);
        *(float4*)(xlds + r * 128 + c4 * 4) = v;
    }
    const int rg = t >> 5, ct = t & 31;
    float acc[4][4];
    {
        float4 bv = *(const float4*)(bias + ct * 4);
        #pragma unroll
        for (int rr = 0; rr < 4; ++rr) {
            acc[rr][0] = bv.x; acc[rr][1] = bv.y; acc[rr][2] = bv.z; acc[rr][3] = bv.w;
        }
    }
    float4 wreg[4];
    #pragma unroll
    for (int p = 0; p < 4; ++p) wreg[p] = *(const float4*)(W + (size_t)(t + 256 * p) * 4);
    for (int kc = 0; kc < 4; ++kc) {
        __syncthreads();  // kc=0: x staged; kc>0: previous chunk's compute done (WAR on wlds)
        #pragma unroll
        for (int p = 0; p < 4; ++p) *(float4*)(wlds + (size_t)(t + 256 * p) * 4) = wreg[p];
        if (kc < 3) {
            #pragma unroll
            for (int p = 0; p < 4; ++p)
                wreg[p] = *(const float4*)(W + (size_t)(kc + 1) * 4096 + (t + 256 * p) * 4);
        }
        __syncthreads();
        #pragma unroll 2
        for (int i2 = 0; i2 < 32; i2 += 4) {
            const int i = kc * 32 + i2;
            float4 xv[4];
            #pragma unroll
            for (int rr = 0; rr < 4; ++rr) xv[rr] = *(const float4*)(xlds + (rg + 8 * rr) * 128 + i);
            #pragma unroll
            for (int qq = 0; qq < 4; ++qq) {
                float4 wv = *(const float4*)(wlds + (i2 + qq) * 128 + ct * 4);
                #pragma unroll
                for (int rr = 0; rr < 4; ++rr) {
                    float xs = ((const float*)&xv[rr])[qq];
                    acc[rr][0] = fmaf(xs, wv.x, acc[rr][0]);
                    acc[rr][1] = fmaf(xs, wv.y, acc[rr][1]);
                    acc[rr][2] = fmaf(xs, wv.z, acc[rr][2]);
                    acc[rr][3] = fmaf(xs, wv.w, acc[rr][3]);
                }
            }
        }
    }
    // store h
    #pragma unroll
    for (int rr = 0; rr < 4; ++rr) {
        int grow = row0 + rg + 8 * rr;
        if (grow < N)
            *(float4*)(hout + (size_t)grow * 128 + ct * 4) =
                make_float4(acc[rr][0], acc[rr][1], acc[rr][2], acc[rr][3]);
    }
    // e-dots: thread's 4 cols are inside head (ct>>2); reduce over 4-lane col group
    const int head = ct >> 2;
    const bool wlane = (ct & 3) == 0;
    if (att0) {
        float4 av = *(const float4*)(att0 + ct * 4);
        #pragma unroll
        for (int rr = 0; rr < 4; ++rr) {
            float p_ = acc[rr][0] * av.x + acc[rr][1] * av.y + acc[rr][2] * av.z + acc[rr][3] * av.w;
            p_ += __shfl_xor(p_, 1);
            p_ += __shfl_xor(p_, 2);
            int grow = row0 + rg + 8 * rr;
            if (wlane && grow < N) e0[(size_t)grow * 8 + head] = p_;
        }
    }
    if (att1) {
        float4 av = *(const float4*)(att1 + ct * 4);
        #pragma unroll
        for (int rr = 0; rr < 4; ++rr) {
            float p_ = acc[rr][0] * av.x + acc[rr][1] * av.y + acc[rr][2] * av.z + acc[rr][3] * av.w;
            p_ += __shfl_xor(p_, 1);
            p_ += __shfl_xor(p_, 2);
            int grow = row0 + rg + 8 * rr;
            if (wlane && grow < N) e1[(size_t)grow * 8 + head] = p_;
        }
    }
    if (att2) {
        float4 av = *(const float4*)(att2 + ct * 4);
        #pragma unroll
        for (int rr = 0; rr < 4; ++rr) {
            float p_ = acc[rr][0] * av.x + acc[rr][1] * av.y + acc[rr][2] * av.z + acc[rr][3] * av.w;
            p_ += __shfl_xor(p_, 1);
            p_ += __shfl_xor(p_, 2);
            int grow = row0 + rg + 8 * rr;
            if (wlane && grow < N) e2[(size_t)grow * 8 + head] = p_;
        }
    }
}

// ---------------- fused CSR build (both graphs in one pass) ----------------
// cnt is a contiguous [2N] array: [0,N) = gene-graph counts, [N,2N) = disease-graph counts.
__global__ void hist2_kernel(const int* __restrict__ dstg, int Eg,
                             const int* __restrict__ dstd, int Ed,
                             int* __restrict__ cnt, int N) {
    int i = blockIdx.x * 256 + threadIdx.x;
    if (i < Eg) atomicAdd(&cnt[dstg[i]], 1);
    else if (i < Eg + Ed) atomicAdd(&cnt[N + dstd[i - Eg]], 1);
}

__global__ void scan_block_reduce(const int* __restrict__ cnt, int N2, int* bsum) {
    __shared__ int s[256];
    int t = threadIdx.x;
    int i = blockIdx.x * 256 + t;
    s[t] = (i < N2) ? cnt[i] : 0;
    __syncthreads();
    for (int o = 128; o > 0; o >>= 1) {
        if (t < o) s[t] += s[t + o];
        __syncthreads();
    }
    if (t == 0) bsum[blockIdx.x] = s[0];
}

__global__ void scan_bsum(const int* __restrict__ bsum, int nb, int* boff) {
    __shared__ int s[1024];
    int t = threadIdx.x;
    int v = (t < nb) ? bsum[t] : 0;
    s[t] = v;
    __syncthreads();
    for (int o = 1; o < 1024; o <<= 1) {
        int add = (t >= o) ? s[t - o] : 0;
        __syncthreads();
        s[t] += add;
        __syncthreads();
    }
    if (t < nb) boff[t] = s[t] - v;  // exclusive
}

// exclusive scan over the combined [2N] counts; region 2 rebased by -Eg (prefix at N == Eg).
// Writes off AND run (scatter cursor) for both graphs -> no d2d memcpy needed.
__global__ void scan_final2(const int* __restrict__ cnt, int N, const int* __restrict__ boff,
                            int Eg, int Ed,
                            int* __restrict__ offg, int* __restrict__ offd,
                            int* __restrict__ rung, int* __restrict__ rund) {
    __shared__ int s[256];
    int t = threadIdx.x;
    int i = blockIdx.x * 256 + t;
    const int N2 = 2 * N;
    int v = (i < N2) ? cnt[i] : 0;
    s[t] = v;
    __syncthreads();
    for (int o = 1; o < 256; o <<= 1) {
        int add = (t >= o) ? s[t - o] : 0;
        __syncthreads();
        s[t] += add;
        __syncthreads();
    }
    int excl = s[t] - v + boff[blockIdx.x];
    if (i < N) {
        offg[i] = excl; rung[i] = excl;
    } else if (i < N2) {
        int e = excl - Eg;
        offd[i - N] = e; rund[i - N] = e;
    }
    if (blockIdx.x == 0 && t == 0) { offg[N] = Eg; offd[N] = Ed; }
}

// fused scatter of SRC ids for both graphs
__global__ void scatter2_kernel(const int* __restrict__ dstg, const int* __restrict__ srcg, int Eg,
                                const int* __restrict__ dstd, const int* __restrict__ srcd, int Ed,
                                int* __restrict__ rung, int* __restrict__ rund,
                                int* __restrict__ outg, int* __restrict__ outd) {
    int i = blockIdx.x * 256 + threadIdx.x;
    if (i < Eg) {
        int p = atomicAdd(&rung[dstg[i]], 1);
        outg[p] = srcg[i];
    } else if (i < Eg + Ed) {
        int j = i - Eg;
        int p = atomicAdd(&rund[dstd[j]], 1);
        outd[p] = srcd[j];
    }
}

// ---------------- per-dst-node softmax aggregation (1 wave per node) ----------------
__global__ __launch_bounds__(256) void aggregate_kernel(
    const float* __restrict__ xs,        // [Ns,128] projected src feats
    const float* __restrict__ esrc,      // [Ns,8]
    const float* __restrict__ edst,      // [Nd,8]
    const int* __restrict__ off,         // [Nd+1]
    const int* __restrict__ srcsorted,   // [E] src ids bucketed by dst
    float* __restrict__ outp,            // [Nd,128]
    int Nd)
{
    __shared__ float exbuf[4][64 * 8];
    const int lane = threadIdx.x & 63;
    const int wslot = threadIdx.x >> 6;
    const int n = blockIdx.x * 4 + wslot;
    if (n >= Nd) return;
    const int o0 = off[n], o1 = off[n + 1];
    const int deg = o1 - o0;
    const int li = lane & 31, half = lane >> 5;
    const int j0 = li * 4;       // this lane's 4 cols (within its half)
    const int hh = li >> 2;      // head owning those cols
    if (deg == 0) {
        if (half == 0) *(float4*)(outp + (size_t)n * 128 + j0) = make_float4(0.f, 0.f, 0.f, 0.f);
        return;
    }
    float ed[8];
    {
        float4 a = *(const float4*)(edst + (size_t)n * 8);
        float4 b = *(const float4*)(edst + (size_t)n * 8 + 4);
        ed[0] = a.x; ed[1] = a.y; ed[2] = a.z; ed[3] = a.w;
        ed[4] = b.x; ed[5] = b.y; ed[6] = b.z; ed[7] = b.w;
    }
    if (deg <= 64) {
        const bool act = lane < deg;
        int s = act ? srcsorted[o0 + lane] : 0;   // coalesced
        float m[8];
        {
            float4 ea = make_float4(0.f, 0.f, 0.f, 0.f), eb = ea;
            if (act) {
                ea = *(const float4*)(esrc + (size_t)s * 8);
                eb = *(const float4*)(esrc + (size_t)s * 8 + 4);
            }
            float a[8] = {ea.x, ea.y, ea.z, ea.w, eb.x, eb.y, eb.z, eb.w};
            #pragma unroll
            for (int h2 = 0; h2 < 8; ++h2) m[h2] = act ? leakyf(a[h2] + ed[h2]) : -1e30f;
        }
        float al[8];
        #pragma unroll
        for (int h2 = 0; h2 < 8; ++h2) al[h2] = m[h2];
        for (int o = 1; o < deg; o <<= 1) {
            #pragma unroll
            for (int h2 = 0; h2 < 8; ++h2) m[h2] = fmaxf(m[h2], __shfl_xor(m[h2], o));
        }
        float exv[8];
        #pragma unroll
        for (int h2 = 0; h2 < 8; ++h2) exv[h2] = act ? __expf(al[h2] - m[h2]) : 0.f;
        *(float4*)(&exbuf[wslot][lane * 8])     = make_float4(exv[0], exv[1], exv[2], exv[3]);
        *(float4*)(&exbuf[wslot][lane * 8 + 4]) = make_float4(exv[4], exv[5], exv[6], exv[7]);
        float4 num = make_float4(0.f, 0.f, 0.f, 0.f);
        float den = 0.f;
        const int iters = (deg + 1) >> 1;
        #pragma unroll 2
        for (int k = 0; k < iters; ++k) {
            int i = 2 * k + half;
            if (i < deg) {
                int si = __shfl(s, i);
                float wgt = exbuf[wslot][i * 8 + hh];
                float4 xv = *(const float4*)(xs + (size_t)si * 128 + j0);
                num.x = fmaf(wgt, xv.x, num.x);
                num.y = fmaf(wgt, xv.y, num.y);
                num.z = fmaf(wgt, xv.z, num.z);
                num.w = fmaf(wgt, xv.w, num.w);
                den += wgt;
            }
        }
        num.x += __shfl_xor(num.x, 32);
        num.y += __shfl_xor(num.y, 32);
        num.z += __shfl_xor(num.z, 32);
        num.w += __shfl_xor(num.w, 32);
        den += __shfl_xor(den, 32);
        if (half == 0) {
            float inv = 1.f / (den + 1e-16f);
            float4 r;
            r.x = fmaxf(num.x * inv, 0.f);
            r.y = fmaxf(num.y * inv, 0.f);
            r.z = fmaxf(num.z * inv, 0.f);
            r.w = fmaxf(num.w * inv, 0.f);
            *(float4*)(outp + (size_t)n * 128 + j0) = r;
        }
        return;
    }
    // ---- slow path (deg > 64) ----
    {
        const int j0b = lane * 2;
        const int h = lane >> 3;
        float m[8];
        #pragma unroll
        for (int hh2 = 0; hh2 < 8; ++hh2) m[hh2] = -1e30f;
        for (int base = 0; base < deg; base += 64) {
            int ii = base + lane;
            bool act = ii < deg;
            int s = srcsorted[o0 + (act ? ii : 0)];
            float4 ea = *(const float4*)(esrc + (size_t)s * 8);
            float4 eb = *(const float4*)(esrc + (size_t)s * 8 + 4);
            float a[8] = {ea.x, ea.y, ea.z, ea.w, eb.x, eb.y, eb.z, eb.w};
            #pragma unroll
            for (int hh2 = 0; hh2 < 8; ++hh2) {
                float v = act ? leakyf(a[hh2] + ed[hh2]) : -1e30f;
                #pragma unroll
                for (int o = 1; o < 64; o <<= 1) v = fmaxf(v, __shfl_xor(v, o));
                m[hh2] = fmaxf(m[hh2], v);
            }
        }
        float mh, edh;
        {
            float t4a = (h & 4) ? m[4] : m[0];
            float t4b = (h & 4) ? m[5] : m[1];
            float t4c = (h & 4) ? m[6] : m[2];
            float t4d = (h & 4) ? m[7] : m[3];
            float t2a = (h & 2) ? t4c : t4a;
            float t2b = (h & 2) ? t4d : t4b;
            mh = (h & 1) ? t2b : t2a;
            float u4a = (h & 4) ? ed[4] : ed[0];
            float u4b = (h & 4) ? ed[5] : ed[1];
            float u4c = (h & 4) ? ed[6] : ed[2];
            float u4d = (h & 4) ? ed[7] : ed[3];
            float u2a = (h & 2) ? u4c : u4a;
            float u2b = (h & 2) ? u4d : u4b;
            edh = (h & 1) ? u2b : u2a;
        }
        float den = 0.f, num0 = 0.f, num1 = 0.f;
        for (int base = 0; base < deg; base += 64) {
            int ii = base + lane;
            bool act = ii < deg;
            int sreg = srcsorted[o0 + (act ? ii : 0)];
            int cl = deg - base;
            if (cl > 64) cl = 64;
            for (int i = 0; i < cl; ++i) {
                int s = __shfl(sreg, i);
                float ev = esrc[(size_t)s * 8 + h];
                float ex = __expf(leakyf(ev + edh) - mh);
                float2 xv = *(const float2*)(xs + (size_t)s * 128 + j0b);
                num0 = fmaf(ex, xv.x, num0);
                num1 = fmaf(ex, xv.y, num1);
                den += ex;
            }
        }
        float inv = 1.f / (den + 1e-16f);
        float r0 = num0 * inv, r1 = num1 * inv;
        r0 = r0 > 0.f ? r0 : 0.f;
        r1 = r1 > 0.f ? r1 : 0.f;
        *(float2*)(outp + (size_t)n * 128 + j0b) = make_float2(r0, r1);
    }
}

// ---------------- fused semantic attention scores for BOTH metapaths ----------------
// Half-tile packing (16 gg rows + 16 dg rows per 32x128 tile) for occupancy; Wk K-chunks
// double-buffered through registers (same pattern as proj_kernel).
__global__ __launch_bounds__(256) void score2_kernel(
    const float* __restrict__ gg, const float* __restrict__ dg,
    const float* __restrict__ Wk, const float* __restrict__ bk, const float* __restrict__ q,
    float* __restrict__ scoreAcc, int N)
{
    __shared__ float tile[32 * 128];
    __shared__ float wlds[32 * 128];
    __shared__ float sred[8];
    const int t = threadIdx.x;
    const int row0 = blockIdx.x * 16;
    #pragma unroll
    for (int p = 0; p < 4; ++p) {
        int idx = t + 256 * p;
        int r = idx >> 5;
        int c4 = idx & 31;
        int gr = row0 + (r & 15);
        const float* srcp = (r < 16) ? gg : dg;
        float4 v = make_float4(0.f, 0.f, 0.f, 0.f);
        if (gr < N) v = *(const float4*)(srcp + (size_t)gr * 128 + c4 * 4);
        *(float4*)(tile + r * 128 + c4 * 4) = v;
    }
    const int rg = t >> 5, ct = t & 31;
    float acc[4][4];
    {
        float4 bv = *(const float4*)(bk + ct * 4);
        #pragma unroll
        for (int rr = 0; rr < 4; ++rr) {
            acc[rr][0] = bv.x; acc[rr][1] = bv.y; acc[rr][2] = bv.z; acc[rr][3] = bv.w;
        }
    }
    float4 wreg[4];
    #pragma unroll
    for (int p = 0; p < 4; ++p) wreg[p] = *(const float4*)(Wk + (size_t)(t + 256 * p) * 4);
    for (int kc = 0; kc < 4; ++kc) {
        __syncthreads();
        #pragma unroll
        for (int p = 0; p < 4; ++p) *(float4*)(wlds + (size_t)(t + 256 * p) * 4) = wreg[p];
        if (kc < 3) {
            #pragma unroll
            for (int p = 0; p < 4; ++p)
                wreg[p] = *(const float4*)(Wk + (size_t)(kc + 1) * 4096 + (t + 256 * p) * 4);
        }
        __syncthreads();
        #pragma unroll 2
        for (int i2 = 0; i2 < 32; i2 += 4) {
            const int i = kc * 32 + i2;
            float4 xv[4];
            #pragma unroll
            for (int rr = 0; rr < 4; ++rr) xv[rr] = *(const float4*)(tile + (rg + 8 * rr) * 128 + i);
            #pragma unroll
            for (int qq = 0; qq < 4; ++qq) {
                float4 wv = *(const float4*)(wlds + (i2 + qq) * 128 + ct * 4);
                #pragma unroll
                for (int rr = 0; rr < 4; ++rr) {
                    float xs = ((const float*)&xv[rr])[qq];
                    acc[rr][0] = fmaf(xs, wv.x, acc[rr][0]);
                    acc[rr][1] = fmaf(xs, wv.y, acc[rr][1]);
                    acc[rr][2] = fmaf(xs, wv.z, acc[rr][2]);
                    acc[rr][3] = fmaf(xs, wv.w, acc[rr][3]);
                }
            }
        }
    }
    float4 qv = *(const float4*)(q + ct * 4);
    float pg = 0.f, pd = 0.f;
    #pragma unroll
    for (int rr = 0; rr < 4; ++rr) {
        int r = rg + 8 * rr;               // tile row
        int grow = row0 + (r & 15);        // global row
        if (grow < N) {
            float p_ = 0.f;
            p_ = fmaf(fast_tanh(acc[rr][0]), qv.x, p_);
            p_ = fmaf(fast_tanh(acc[rr][1]), qv.y, p_);
            p_ = fmaf(fast_tanh(acc[rr][2]), qv.z, p_);
            p_ = fmaf(fast_tanh(acc[rr][3]), qv.w, p_);
            if (r < 16) pg += p_; else pd += p_;
        }
    }
    #pragma unroll
    for (int o = 1; o < 64; o <<= 1) {
        pg += __shfl_xor(pg, o);
        pd += __shfl_xor(pd, o);
    }
    if ((t & 63) == 0) {
        sred[(t >> 6) * 2] = pg;
        sred[(t >> 6) * 2 + 1] = pd;
    }
    __syncthreads();
    if (t == 0) {
        float sg = sred[0] + sred[2] + sred[4] + sred[6];
        float sd = sred[1] + sred[3] + sred[5] + sred[7];
        int slot = blockIdx.x & 63;
        atomicAdd(&scoreAcc[slot], sg);
        atomicAdd(&scoreAcc[64 + slot], sd);
    }
}

// ---------------- tiny: reduce 2x64 score slots -> softmax betas ----------------
__global__ void beta_kernel(float* __restrict__ scoreAcc, float invN) {
    int t = threadIdx.x;  // 64 threads
    float v0 = scoreAcc[t];
    float v1 = scoreAcc[64 + t];
    #pragma unroll
    for (int o = 1; o < 64; o <<= 1) {
        v0 += __shfl_xor(v0, o);
        v1 += __shfl_xor(v1, o);
    }
    if (t == 0) {
        float s0 = v0 * invN, s1 = v1 * invN;
        float mx = fmaxf(s0, s1);
        float e0 = __expf(s0 - mx), e1 = __expf(s1 - mx);
        float inv = 1.f / (e0 + e1);
        scoreAcc[128] = e0 * inv;
        scoreAcc[129] = e1 * inv;
    }
}

// ---------------- final: beta blend + @W_lin + b_lin (W_lin staged in LDS) ----------------
__global__ __launch_bounds__(256) void final_kernel(
    const float* __restrict__ gg, const float* __restrict__ dg,
    const float* __restrict__ beta,   // scoreAcc+128: {beta0, beta1}
    const float* __restrict__ Wl, const float* __restrict__ bl,
    float* __restrict__ outp, int N)
{
    __shared__ float wlds[128 * 64];  // 32 KB — whole W_lin
    __shared__ float glds[32 * 128];  // 16 KB — blended tile
    const int t = threadIdx.x;
    #pragma unroll
    for (int p = 0; p < 8; ++p) {
        int idx = (t + 256 * p) * 4;
        *(float4*)(wlds + idx) = *(const float4*)(Wl + idx);
    }
    const float bet0 = beta[0], bet1 = beta[1];
    const int row0 = blockIdx.x * 32;
    #pragma unroll
    for (int p = 0; p < 4; ++p) {
        int idx = t + 256 * p;
        int r = idx >> 5;
        int c4 = idx & 31;
        float4 a = make_float4(0.f, 0.f, 0.f, 0.f), b = a, g;
        if (row0 + r < N) {
            a = *(const float4*)(gg + (size_t)(row0 + r) * 128 + c4 * 4);
            b = *(const float4*)(dg + (size_t)(row0 + r) * 128 + c4 * 4);
        }
        g.x = bet0 * a.x + bet1 * b.x;
        g.y = bet0 * a.y + bet1 * b.y;
        g.z = bet0 * a.z + bet1 * b.z;
        g.w = bet0 * a.w + bet1 * b.w;
        *(float4*)(glds + r * 128 + c4 * 4) = g;
    }
    __syncthreads();
    const int rg = t >> 5, ct = t & 31;
    float acc[4][2];
    {
        float2 bv = *(const float2*)(bl + ct * 2);
        #pragma unroll
        for (int rr = 0; rr < 4; ++rr) { acc[rr][0] = bv.x; acc[rr][1] = bv.y; }
    }
    #pragma unroll 2
    for (int i = 0; i < 128; i += 4) {
        float4 xv[4];
        #pragma unroll
        for (int rr = 0; rr < 4; ++rr) xv[rr] = *(const float4*)(glds + (rg + 8 * rr) * 128 + i);
        #pragma unroll
        for (int qq = 0; qq < 4; ++qq) {
            float2 wv = *(const float2*)(wlds + (i + qq) * 64 + ct * 2);
            #pragma unroll
            for (int rr = 0; rr < 4; ++rr) {
                float xs = ((const float*)&xv[rr])[qq];
                acc[rr][0] = fmaf(xs, wv.x, acc[rr][0]);
                acc[rr][1] = fmaf(xs, wv.y, acc[rr][1]);
            }
        }
    }
    #pragma unroll
    for (int rr = 0; rr < 4; ++rr) {
        int grow = row0 + rg + 8 * rr;
        if (grow < N)
            *(float2*)(outp + (size_t)grow * 64 + ct * 2) = make_float2(acc[rr][0], acc[rr][1]);
    }
}

extern "C" void kernel_launch(void* const* d_in, const int* in_sizes, int n_in,
                              void* d_out, int out_size, void* d_ws, size_t ws_size,
                              hipStream_t stream) {
    (void)n_in; (void)out_size; (void)ws_size;
    const float* x_gene = (const float*)d_in[0];
    const float* x_dis  = (const float*)d_in[1];
    const int* eg_src   = (const int*)d_in[2];
    const int* eg_dst   = (const int*)d_in[3];
    const int* edg_src  = (const int*)d_in[4];
    const int* edg_dst  = (const int*)d_in[5];
    const float* W_gene = (const float*)d_in[6];
    const float* b_gene = (const float*)d_in[7];
    const float* W_dis  = (const float*)d_in[8];
    const float* b_dis  = (const float*)d_in[9];
    const float* att_src_gg = (const float*)d_in[10];
    const float* att_dst_gg = (const float*)d_in[11];
    const float* att_src_dg = (const float*)d_in[12];
    const float* att_dst_dg = (const float*)d_in[13];
    const float* Wk    = (const float*)d_in[14];
    const float* bk    = (const float*)d_in[15];
    const float* q     = (const float*)d_in[16];
    const float* W_lin = (const float*)d_in[17];
    const float* b_lin = (const float*)d_in[18];
    float* out = (float*)d_out;

    const int NG_ = in_sizes[0] / 128;
    const int ND_ = in_sizes[1] / 128;
    const int EG_ = in_sizes[2];
    const int EDG_ = in_sizes[4];

    char* w = (char*)d_ws;
    auto alloc = [&](size_t bytes) -> char* {
        char* p = w;
        w += (bytes + 255) & ~(size_t)255;
        return p;
    };
    float* hg       = (float*)alloc((size_t)NG_ * 128 * 4);
    float* hd       = (float*)alloc((size_t)ND_ * 128 * 4);
    float* e_src_gg = (float*)alloc((size_t)NG_ * 8 * 4);
    float* e_dst_gg = (float*)alloc((size_t)NG_ * 8 * 4);
    float* e_dst_dg = (float*)alloc((size_t)NG_ * 8 * 4);
    float* e_src_dg = (float*)alloc((size_t)ND_ * 8 * 4);
    float* out_gg   = (float*)alloc((size_t)NG_ * 128 * 4);
    int* cnt   = (int*)alloc((size_t)(2 * NG_) * 4);      // [2N] combined counts
    int* offg  = (int*)alloc((size_t)(NG_ + 1) * 4);
    int* offd  = (int*)alloc((size_t)(NG_ + 1) * 4);
    int* rung  = (int*)alloc((size_t)NG_ * 4);
    int* rund  = (int*)alloc((size_t)NG_ * 4);
    int* srcs_g = (int*)alloc((size_t)EG_ * 4);
    int* srcs_d = (int*)alloc((size_t)EDG_ * 4);
    int* bsum  = (int*)alloc(8192);
    int* boff  = (int*)alloc(8192);
    float* score = (float*)alloc(1024);
    float* out_dg = hg;  // hg is dead after the gg aggregation; alias to save 51 MB

    const int N2 = 2 * NG_;
    const int nb2 = (N2 + 255) / 256;   // 782 <= 1024, fits single-block scan_bsum

    // 1. projections (+ e-vectors)
    proj_kernel<<<(NG_ + 31) / 32, 256, 0, stream>>>(
        x_gene, W_gene, b_gene, hg, NG_,
        att_src_gg, e_src_gg, att_dst_gg, e_dst_gg, att_dst_dg, e_dst_dg);
    proj_kernel<<<(ND_ + 31) / 32, 256, 0, stream>>>(
        x_dis, W_dis, b_dis, hd, ND_,
        att_src_dg, e_src_dg, (const float*)nullptr, (float*)nullptr,
        (const float*)nullptr, (float*)nullptr);

    // 2. fused CSR build (both graphs)
    hipMemsetAsync(cnt, 0, (size_t)N2 * 4, stream);
    hist2_kernel<<<(EG_ + EDG_ + 255) / 256, 256, 0, stream>>>(
        eg_dst, EG_, edg_dst, EDG_, cnt, NG_);
    scan_block_reduce<<<nb2, 256, 0, stream>>>(cnt, N2, bsum);
    scan_bsum<<<1, 1024, 0, stream>>>(bsum, nb2, boff);
    scan_final2<<<nb2, 256, 0, stream>>>(cnt, NG_, boff, EG_, EDG_, offg, offd, rung, rund);
    scatter2_kernel<<<(EG_ + EDG_ + 255) / 256, 256, 0, stream>>>(
        eg_dst, eg_src, EG_, edg_dst, edg_src, EDG_, rung, rund, srcs_g, srcs_d);

    // 3. aggregates (sequential: out_dg aliases hg, which gg-aggregate reads)
    aggregate_kernel<<<(NG_ + 3) / 4, 256, 0, stream>>>(
        hg, e_src_gg, e_dst_gg, offg, srcs_g, out_gg, NG_);
    aggregate_kernel<<<(NG_ + 3) / 4, 256, 0, stream>>>(
        hd, e_src_dg, e_dst_dg, offd, srcs_d, out_dg, NG_);

    // 4. fused semantic attention scores (both metapaths, one pass) + beta
    hipMemsetAsync(score, 0, 512, stream);
    score2_kernel<<<(NG_ + 15) / 16, 256, 0, stream>>>(out_gg, out_dg, Wk, bk, q, score, NG_);
    beta_kernel<<<1, 64, 0, stream>>>(score, 1.0f / (float)NG_);

    // 5. blend + final linear
    final_kernel<<<(NG_ + 31) / 32, 256, 0, stream>>>(
        out_gg, out_dg, score + 128, W_lin, b_lin, out, NG_);
}

// Round 9
// 567.540 us; speedup vs baseline: 1.1322x; 1.1322x over previous
//
#include <hip/hip_runtime.h>
#include <cstdint>
#include <cstddef>

#define NEG_SLOPE 0.2f

__device__ __forceinline__ float leakyf(float x) { return x > 0.f ? x : NEG_SLOPE * x; }
__device__ __forceinline__ float fast_tanh(float x) {
    float e = __expf(2.f * x);
    return 1.f - 2.f / (e + 1.f);
}

// ---------------- projection (x@W+b) + per-head attention dots ----------------
// block 256 = 8 row-groups x 32 col-threads; 32 rows/block, thread = 4 rows x 4 contiguous cols.
// W staged in LDS by 32-row K-chunks (synchronous barrier-staged copy — reg-dbuf variant
// REGRESSED in round 8; compiler schedules the simple copy better).
__global__ __launch_bounds__(256) void proj_kernel(
    const float* __restrict__ x, const float* __restrict__ W, const float* __restrict__ bias,
    float* __restrict__ hout, int N,
    const float* __restrict__ att0, float* __restrict__ e0,
    const float* __restrict__ att1, float* __restrict__ e1,
    const float* __restrict__ att2, float* __restrict__ e2)
{
    __shared__ float xlds[32 * 128];  // 16 KB: x tile
    __shared__ float wlds[32 * 128];  // 16 KB: W K-chunk
    const int t = threadIdx.x;
    const int row0 = blockIdx.x * 32;
    #pragma unroll
    for (int p = 0; p < 4; ++p) {
        int idx = t + 256 * p;
        int r = idx >> 5;
        int c4 = idx & 31;
        float4 v = make_float4(0.f, 0.f, 0.f, 0.f);
        if (row0 + r < N) v = *(const float4*)(x + (size_t)(row0 + r) * 128 + c4 * 4);
        *(float4*)(xlds + r * 128 + c4 * 4) = v;
    }
    const int rg = t >> 5, ct = t & 31;
    float acc[4][4];
    {
        float4 bv = *(const float4*)(bias + ct * 4);
        #pragma unroll
        for (int rr = 0; rr < 4; ++rr) {
            acc[rr][0] = bv.x; acc[rr][1] = bv.y; acc[rr][2] = bv.z; acc[rr][3] = bv.w;
        }
    }
    for (int kc = 0; kc < 4; ++kc) {
        __syncthreads();  // kc=0: x staged; kc>0: previous chunk's compute done (WAR on wlds)
        #pragma unroll
        for (int p = 0; p < 4; ++p) {
            int idx = t + 256 * p;
            *(float4*)(wlds + idx * 4) = *(const float4*)(W + (size_t)kc * 4096 + idx * 4);
        }
        __syncthreads();
        #pragma unroll 2
        for (int i2 = 0; i2 < 32; i2 += 4) {
            const int i = kc * 32 + i2;
            float4 xv[4];
            #pragma unroll
            for (int rr = 0; rr < 4; ++rr) xv[rr] = *(const float4*)(xlds + (rg + 8 * rr) * 128 + i);
            #pragma unroll
            for (int qq = 0; qq < 4; ++qq) {
                float4 wv = *(const float4*)(wlds + (i2 + qq) * 128 + ct * 4);
                #pragma unroll
                for (int rr = 0; rr < 4; ++rr) {
                    float xs = ((const float*)&xv[rr])[qq];
                    acc[rr][0] = fmaf(xs, wv.x, acc[rr][0]);
                    acc[rr][1] = fmaf(xs, wv.y, acc[rr][1]);
                    acc[rr][2] = fmaf(xs, wv.z, acc[rr][2]);
                    acc[rr][3] = fmaf(xs, wv.w, acc[rr][3]);
                }
            }
        }
    }
    // store h
    #pragma unroll
    for (int rr = 0; rr < 4; ++rr) {
        int grow = row0 + rg + 8 * rr;
        if (grow < N)
            *(float4*)(hout + (size_t)grow * 128 + ct * 4) =
                make_float4(acc[rr][0], acc[rr][1], acc[rr][2], acc[rr][3]);
    }
    // e-dots: thread's 4 cols are inside head (ct>>2); reduce over 4-lane col group
    const int head = ct >> 2;
    const bool wlane = (ct & 3) == 0;
    if (att0) {
        float4 av = *(const float4*)(att0 + ct * 4);
        #pragma unroll
        for (int rr = 0; rr < 4; ++rr) {
            float p_ = acc[rr][0] * av.x + acc[rr][1] * av.y + acc[rr][2] * av.z + acc[rr][3] * av.w;
            p_ += __shfl_xor(p_, 1);
            p_ += __shfl_xor(p_, 2);
            int grow = row0 + rg + 8 * rr;
            if (wlane && grow < N) e0[(size_t)grow * 8 + head] = p_;
        }
    }
    if (att1) {
        float4 av = *(const float4*)(att1 + ct * 4);
        #pragma unroll
        for (int rr = 0; rr < 4; ++rr) {
            float p_ = acc[rr][0] * av.x + acc[rr][1] * av.y + acc[rr][2] * av.z + acc[rr][3] * av.w;
            p_ += __shfl_xor(p_, 1);
            p_ += __shfl_xor(p_, 2);
            int grow = row0 + rg + 8 * rr;
            if (wlane && grow < N) e1[(size_t)grow * 8 + head] = p_;
        }
    }
    if (att2) {
        float4 av = *(const float4*)(att2 + ct * 4);
        #pragma unroll
        for (int rr = 0; rr < 4; ++rr) {
            float p_ = acc[rr][0] * av.x + acc[rr][1] * av.y + acc[rr][2] * av.z + acc[rr][3] * av.w;
            p_ += __shfl_xor(p_, 1);
            p_ += __shfl_xor(p_, 2);
            int grow = row0 + rg + 8 * rr;
            if (wlane && grow < N) e2[(size_t)grow * 8 + head] = p_;
        }
    }
}

// ---------------- fused CSR build (both graphs in one pass) ----------------
// cnt is a contiguous [2N] array: [0,N) = gene-graph counts, [N,2N) = disease-graph counts.
__global__ void hist2_kernel(const int* __restrict__ dstg, int Eg,
                             const int* __restrict__ dstd, int Ed,
                             int* __restrict__ cnt, int N) {
    int i = blockIdx.x * 256 + threadIdx.x;
    if (i < Eg) atomicAdd(&cnt[dstg[i]], 1);
    else if (i < Eg + Ed) atomicAdd(&cnt[N + dstd[i - Eg]], 1);
}

__global__ void scan_block_reduce(const int* __restrict__ cnt, int N2, int* bsum) {
    __shared__ int s[256];
    int t = threadIdx.x;
    int i = blockIdx.x * 256 + t;
    s[t] = (i < N2) ? cnt[i] : 0;
    __syncthreads();
    for (int o = 128; o > 0; o >>= 1) {
        if (t < o) s[t] += s[t + o];
        __syncthreads();
    }
    if (t == 0) bsum[blockIdx.x] = s[0];
}

__global__ void scan_bsum(const int* __restrict__ bsum, int nb, int* boff) {
    __shared__ int s[1024];
    int t = threadIdx.x;
    int v = (t < nb) ? bsum[t] : 0;
    s[t] = v;
    __syncthreads();
    for (int o = 1; o < 1024; o <<= 1) {
        int add = (t >= o) ? s[t - o] : 0;
        __syncthreads();
        s[t] += add;
        __syncthreads();
    }
    if (t < nb) boff[t] = s[t] - v;  // exclusive
}

// exclusive scan over the combined [2N] counts; region 2 rebased by -Eg (prefix at N == Eg).
// Writes off AND run (scatter cursor) for both graphs -> no d2d memcpy needed.
__global__ void scan_final2(const int* __restrict__ cnt, int N, const int* __restrict__ boff,
                            int Eg, int Ed,
                            int* __restrict__ offg, int* __restrict__ offd,
                            int* __restrict__ rung, int* __restrict__ rund) {
    __shared__ int s[256];
    int t = threadIdx.x;
    int i = blockIdx.x * 256 + t;
    const int N2 = 2 * N;
    int v = (i < N2) ? cnt[i] : 0;
    s[t] = v;
    __syncthreads();
    for (int o = 1; o < 256; o <<= 1) {
        int add = (t >= o) ? s[t - o] : 0;
        __syncthreads();
        s[t] += add;
        __syncthreads();
    }
    int excl = s[t] - v + boff[blockIdx.x];
    if (i < N) {
        offg[i] = excl; rung[i] = excl;
    } else if (i < N2) {
        int e = excl - Eg;
        offd[i - N] = e; rund[i - N] = e;
    }
    if (blockIdx.x == 0 && t == 0) { offg[N] = Eg; offd[N] = Ed; }
}

// fused scatter of SRC ids for both graphs
__global__ void scatter2_kernel(const int* __restrict__ dstg, const int* __restrict__ srcg, int Eg,
                                const int* __restrict__ dstd, const int* __restrict__ srcd, int Ed,
                                int* __restrict__ rung, int* __restrict__ rund,
                                int* __restrict__ outg, int* __restrict__ outd) {
    int i = blockIdx.x * 256 + threadIdx.x;
    if (i < Eg) {
        int p = atomicAdd(&rung[dstg[i]], 1);
        outg[p] = srcg[i];
    } else if (i < Eg + Ed) {
        int j = i - Eg;
        int p = atomicAdd(&rund[dstd[j]], 1);
        outd[p] = srcd[j];
    }
}

// ---------------- per-dst-node softmax aggregation (1 wave per node) ----------------
__global__ __launch_bounds__(256) void aggregate_kernel(
    const float* __restrict__ xs,        // [Ns,128] projected src feats
    const float* __restrict__ esrc,      // [Ns,8]
    const float* __restrict__ edst,      // [Nd,8]
    const int* __restrict__ off,         // [Nd+1]
    const int* __restrict__ srcsorted,   // [E] src ids bucketed by dst
    float* __restrict__ outp,            // [Nd,128]
    int Nd)
{
    __shared__ float exbuf[4][64 * 8];
    const int lane = threadIdx.x & 63;
    const int wslot = threadIdx.x >> 6;
    const int n = blockIdx.x * 4 + wslot;
    if (n >= Nd) return;
    const int o0 = off[n], o1 = off[n + 1];
    const int deg = o1 - o0;
    const int li = lane & 31, half = lane >> 5;
    const int j0 = li * 4;       // this lane's 4 cols (within its half)
    const int hh = li >> 2;      // head owning those cols
    if (deg == 0) {
        if (half == 0) *(float4*)(outp + (size_t)n * 128 + j0) = make_float4(0.f, 0.f, 0.f, 0.f);
        return;
    }
    float ed[8];
    {
        float4 a = *(const float4*)(edst + (size_t)n * 8);
        float4 b = *(const float4*)(edst + (size_t)n * 8 + 4);
        ed[0] = a.x; ed[1] = a.y; ed[2] = a.z; ed[3] = a.w;
        ed[4] = b.x; ed[5] = b.y; ed[6] = b.z; ed[7] = b.w;
    }
    if (deg <= 64) {
        const bool act = lane < deg;
        int s = act ? srcsorted[o0 + lane] : 0;   // coalesced
        float m[8];
        {
            float4 ea = make_float4(0.f, 0.f, 0.f, 0.f), eb = ea;
            if (act) {
                ea = *(const float4*)(esrc + (size_t)s * 8);
                eb = *(const float4*)(esrc + (size_t)s * 8 + 4);
            }
            float a[8] = {ea.x, ea.y, ea.z, ea.w, eb.x, eb.y, eb.z, eb.w};
            #pragma unroll
            for (int h2 = 0; h2 < 8; ++h2) m[h2] = act ? leakyf(a[h2] + ed[h2]) : -1e30f;
        }
        float al[8];
        #pragma unroll
        for (int h2 = 0; h2 < 8; ++h2) al[h2] = m[h2];
        for (int o = 1; o < deg; o <<= 1) {
            #pragma unroll
            for (int h2 = 0; h2 < 8; ++h2) m[h2] = fmaxf(m[h2], __shfl_xor(m[h2], o));
        }
        float exv[8];
        #pragma unroll
        for (int h2 = 0; h2 < 8; ++h2) exv[h2] = act ? __expf(al[h2] - m[h2]) : 0.f;
        *(float4*)(&exbuf[wslot][lane * 8])     = make_float4(exv[0], exv[1], exv[2], exv[3]);
        *(float4*)(&exbuf[wslot][lane * 8 + 4]) = make_float4(exv[4], exv[5], exv[6], exv[7]);
        float4 num = make_float4(0.f, 0.f, 0.f, 0.f);
        float den = 0.f;
        const int iters = (deg + 1) >> 1;
        #pragma unroll 2
        for (int k = 0; k < iters; ++k) {
            int i = 2 * k + half;
            if (i < deg) {
                int si = __shfl(s, i);
                float wgt = exbuf[wslot][i * 8 + hh];
                float4 xv = *(const float4*)(xs + (size_t)si * 128 + j0);
                num.x = fmaf(wgt, xv.x, num.x);
                num.y = fmaf(wgt, xv.y, num.y);
                num.z = fmaf(wgt, xv.z, num.z);
                num.w = fmaf(wgt, xv.w, num.w);
                den += wgt;
            }
        }
        num.x += __shfl_xor(num.x, 32);
        num.y += __shfl_xor(num.y, 32);
        num.z += __shfl_xor(num.z, 32);
        num.w += __shfl_xor(num.w, 32);
        den += __shfl_xor(den, 32);
        if (half == 0) {
            float inv = 1.f / (den + 1e-16f);
            float4 r;
            r.x = fmaxf(num.x * inv, 0.f);
            r.y = fmaxf(num.y * inv, 0.f);
            r.z = fmaxf(num.z * inv, 0.f);
            r.w = fmaxf(num.w * inv, 0.f);
            *(float4*)(outp + (size_t)n * 128 + j0) = r;
        }
        return;
    }
    // ---- slow path (deg > 64) ----
    {
        const int j0b = lane * 2;
        const int h = lane >> 3;
        float m[8];
        #pragma unroll
        for (int hh2 = 0; hh2 < 8; ++hh2) m[hh2] = -1e30f;
        for (int base = 0; base < deg; base += 64) {
            int ii = base + lane;
            bool act = ii < deg;
            int s = srcsorted[o0 + (act ? ii : 0)];
            float4 ea = *(const float4*)(esrc + (size_t)s * 8);
            float4 eb = *(const float4*)(esrc + (size_t)s * 8 + 4);
            float a[8] = {ea.x, ea.y, ea.z, ea.w, eb.x, eb.y, eb.z, eb.w};
            #pragma unroll
            for (int hh2 = 0; hh2 < 8; ++hh2) {
                float v = act ? leakyf(a[hh2] + ed[hh2]) : -1e30f;
                #pragma unroll
                for (int o = 1; o < 64; o <<= 1) v = fmaxf(v, __shfl_xor(v, o));
                m[hh2] = fmaxf(m[hh2], v);
            }
        }
        float mh, edh;
        {
            float t4a = (h & 4) ? m[4] : m[0];
            float t4b = (h & 4) ? m[5] : m[1];
            float t4c = (h & 4) ? m[6] : m[2];
            float t4d = (h & 4) ? m[7] : m[3];
            float t2a = (h & 2) ? t4c : t4a;
            float t2b = (h & 2) ? t4d : t4b;
            mh = (h & 1) ? t2b : t2a;
            float u4a = (h & 4) ? ed[4] : ed[0];
            float u4b = (h & 4) ? ed[5] : ed[1];
            float u4c = (h & 4) ? ed[6] : ed[2];
            float u4d = (h & 4) ? ed[7] : ed[3];
            float u2a = (h & 2) ? u4c : u4a;
            float u2b = (h & 2) ? u4d : u4b;
            edh = (h & 1) ? u2b : u2a;
        }
        float den = 0.f, num0 = 0.f, num1 = 0.f;
        for (int base = 0; base < deg; base += 64) {
            int ii = base + lane;
            bool act = ii < deg;
            int sreg = srcsorted[o0 + (act ? ii : 0)];
            int cl = deg - base;
            if (cl > 64) cl = 64;
            for (int i = 0; i < cl; ++i) {
                int s = __shfl(sreg, i);
                float ev = esrc[(size_t)s * 8 + h];
                float ex = __expf(leakyf(ev + edh) - mh);
                float2 xv = *(const float2*)(xs + (size_t)s * 128 + j0b);
                num0 = fmaf(ex, xv.x, num0);
                num1 = fmaf(ex, xv.y, num1);
                den += ex;
            }
        }
        float inv = 1.f / (den + 1e-16f);
        float r0 = num0 * inv, r1 = num1 * inv;
        r0 = r0 > 0.f ? r0 : 0.f;
        r1 = r1 > 0.f ? r1 : 0.f;
        *(float2*)(outp + (size_t)n * 128 + j0b) = make_float2(r0, r1);
    }
}

// ---------------- fused semantic attention scores for BOTH metapaths ----------------
// Half-tile packing (16 gg rows + 16 dg rows per 32x128 tile) for occupancy; Wk staged in
// LDS by synchronous K-chunks (round-7 proven version).
__global__ __launch_bounds__(256) void score2_kernel(
    const float* __restrict__ gg, const float* __restrict__ dg,
    const float* __restrict__ Wk, const float* __restrict__ bk, const float* __restrict__ q,
    float* __restrict__ scoreAcc, int N)
{
    __shared__ float tile[32 * 128];
    __shared__ float wlds[32 * 128];
    __shared__ float sred[8];
    const int t = threadIdx.x;
    const int row0 = blockIdx.x * 16;
    #pragma unroll
    for (int p = 0; p < 4; ++p) {
        int idx = t + 256 * p;
        int r = idx >> 5;
        int c4 = idx & 31;
        int gr = row0 + (r & 15);
        const float* srcp = (r < 16) ? gg : dg;
        float4 v = make_float4(0.f, 0.f, 0.f, 0.f);
        if (gr < N) v = *(const float4*)(srcp + (size_t)gr * 128 + c4 * 4);
        *(float4*)(tile + r * 128 + c4 * 4) = v;
    }
    const int rg = t >> 5, ct = t & 31;
    float acc[4][4];
    {
        float4 bv = *(const float4*)(bk + ct * 4);
        #pragma unroll
        for (int rr = 0; rr < 4; ++rr) {
            acc[rr][0] = bv.x; acc[rr][1] = bv.y; acc[rr][2] = bv.z; acc[rr][3] = bv.w;
        }
    }
    for (int kc = 0; kc < 4; ++kc) {
        __syncthreads();
        #pragma unroll
        for (int p = 0; p < 4; ++p) {
            int idx = t + 256 * p;
            *(float4*)(wlds + idx * 4) = *(const float4*)(Wk + (size_t)kc * 4096 + idx * 4);
        }
        __syncthreads();
        #pragma unroll 2
        for (int i2 = 0; i2 < 32; i2 += 4) {
            const int i = kc * 32 + i2;
            float4 xv[4];
            #pragma unroll
            for (int rr = 0; rr < 4; ++rr) xv[rr] = *(const float4*)(tile + (rg + 8 * rr) * 128 + i);
            #pragma unroll
            for (int qq = 0; qq < 4; ++qq) {
                float4 wv = *(const float4*)(wlds + (i2 + qq) * 128 + ct * 4);
                #pragma unroll
                for (int rr = 0; rr < 4; ++rr) {
                    float xs = ((const float*)&xv[rr])[qq];
                    acc[rr][0] = fmaf(xs, wv.x, acc[rr][0]);
                    acc[rr][1] = fmaf(xs, wv.y, acc[rr][1]);
                    acc[rr][2] = fmaf(xs, wv.z, acc[rr][2]);
                    acc[rr][3] = fmaf(xs, wv.w, acc[rr][3]);
                }
            }
        }
    }
    float4 qv = *(const float4*)(q + ct * 4);
    float pg = 0.f, pd = 0.f;
    #pragma unroll
    for (int rr = 0; rr < 4; ++rr) {
        int r = rg + 8 * rr;               // tile row
        int grow = row0 + (r & 15);        // global row
        if (grow < N) {
            float p_ = 0.f;
            p_ = fmaf(fast_tanh(acc[rr][0]), qv.x, p_);
            p_ = fmaf(fast_tanh(acc[rr][1]), qv.y, p_);
            p_ = fmaf(fast_tanh(acc[rr][2]), qv.z, p_);
            p_ = fmaf(fast_tanh(acc[rr][3]), qv.w, p_);
            if (r < 16) pg += p_; else pd += p_;
        }
    }
    #pragma unroll
    for (int o = 1; o < 64; o <<= 1) {
        pg += __shfl_xor(pg, o);
        pd += __shfl_xor(pd, o);
    }
    if ((t & 63) == 0) {
        sred[(t >> 6) * 2] = pg;
        sred[(t >> 6) * 2 + 1] = pd;
    }
    __syncthreads();
    if (t == 0) {
        float sg = sred[0] + sred[2] + sred[4] + sred[6];
        float sd = sred[1] + sred[3] + sred[5] + sred[7];
        int slot = blockIdx.x & 63;
        atomicAdd(&scoreAcc[slot], sg);
        atomicAdd(&scoreAcc[64 + slot], sd);
    }
}

// ---------------- tiny: reduce 2x64 score slots -> softmax betas ----------------
__global__ void beta_kernel(float* __restrict__ scoreAcc, float invN) {
    int t = threadIdx.x;  // 64 threads
    float v0 = scoreAcc[t];
    float v1 = scoreAcc[64 + t];
    #pragma unroll
    for (int o = 1; o < 64; o <<= 1) {
        v0 += __shfl_xor(v0, o);
        v1 += __shfl_xor(v1, o);
    }
    if (t == 0) {
        float s0 = v0 * invN, s1 = v1 * invN;
        float mx = fmaxf(s0, s1);
        float e0 = __expf(s0 - mx), e1 = __expf(s1 - mx);
        float inv = 1.f / (e0 + e1);
        scoreAcc[128] = e0 * inv;
        scoreAcc[129] = e1 * inv;
    }
}

// ---------------- final: beta blend + @W_lin + b_lin (W_lin staged in LDS) ----------------
__global__ __launch_bounds__(256) void final_kernel(
    const float* __restrict__ gg, const float* __restrict__ dg,
    const float* __restrict__ beta,   // scoreAcc+128: {beta0, beta1}
    const float* __restrict__ Wl, const float* __restrict__ bl,
    float* __restrict__ outp, int N)
{
    __shared__ float wlds[128 * 64];  // 32 KB — whole W_lin
    __shared__ float glds[32 * 128];  // 16 KB — blended tile
    const int t = threadIdx.x;
    #pragma unroll
    for (int p = 0; p < 8; ++p) {
        int idx = (t + 256 * p) * 4;
        *(float4*)(wlds + idx) = *(const float4*)(Wl + idx);
    }
    const float bet0 = beta[0], bet1 = beta[1];
    const int row0 = blockIdx.x * 32;
    #pragma unroll
    for (int p = 0; p < 4; ++p) {
        int idx = t + 256 * p;
        int r = idx >> 5;
        int c4 = idx & 31;
        float4 a = make_float4(0.f, 0.f, 0.f, 0.f), b = a, g;
        if (row0 + r < N) {
            a = *(const float4*)(gg + (size_t)(row0 + r) * 128 + c4 * 4);
            b = *(const float4*)(dg + (size_t)(row0 + r) * 128 + c4 * 4);
        }
        g.x = bet0 * a.x + bet1 * b.x;
        g.y = bet0 * a.y + bet1 * b.y;
        g.z = bet0 * a.z + bet1 * b.z;
        g.w = bet0 * a.w + bet1 * b.w;
        *(float4*)(glds + r * 128 + c4 * 4) = g;
    }
    __syncthreads();
    const int rg = t >> 5, ct = t & 31;
    float acc[4][2];
    {
        float2 bv = *(const float2*)(bl + ct * 2);
        #pragma unroll
        for (int rr = 0; rr < 4; ++rr) { acc[rr][0] = bv.x; acc[rr][1] = bv.y; }
    }
    #pragma unroll 2
    for (int i = 0; i < 128; i += 4) {
        float4 xv[4];
        #pragma unroll
        for (int rr = 0; rr < 4; ++rr) xv[rr] = *(const float4*)(glds + (rg + 8 * rr) * 128 + i);
        #pragma unroll
        for (int qq = 0; qq < 4; ++qq) {
            float2 wv = *(const float2*)(wlds + (i + qq) * 64 + ct * 2);
            #pragma unroll
            for (int rr = 0; rr < 4; ++rr) {
                float xs = ((const float*)&xv[rr])[qq];
                acc[rr][0] = fmaf(xs, wv.x, acc[rr][0]);
                acc[rr][1] = fmaf(xs, wv.y, acc[rr][1]);
            }
        }
    }
    #pragma unroll
    for (int rr = 0; rr < 4; ++rr) {
        int grow = row0 + rg + 8 * rr;
        if (grow < N)
            *(float2*)(outp + (size_t)grow * 64 + ct * 2) = make_float2(acc[rr][0], acc[rr][1]);
    }
}

extern "C" void kernel_launch(void* const* d_in, const int* in_sizes, int n_in,
                              void* d_out, int out_size, void* d_ws, size_t ws_size,
                              hipStream_t stream) {
    (void)n_in; (void)out_size; (void)ws_size;
    const float* x_gene = (const float*)d_in[0];
    const float* x_dis  = (const float*)d_in[1];
    const int* eg_src   = (const int*)d_in[2];
    const int* eg_dst   = (const int*)d_in[3];
    const int* edg_src  = (const int*)d_in[4];
    const int* edg_dst  = (const int*)d_in[5];
    const float* W_gene = (const float*)d_in[6];
    const float* b_gene = (const float*)d_in[7];
    const float* W_dis  = (const float*)d_in[8];
    const float* b_dis  = (const float*)d_in[9];
    const float* att_src_gg = (const float*)d_in[10];
    const float* att_dst_gg = (const float*)d_in[11];
    const float* att_src_dg = (const float*)d_in[12];
    const float* att_dst_dg = (const float*)d_in[13];
    const float* Wk    = (const float*)d_in[14];
    const float* bk    = (const float*)d_in[15];
    const float* q     = (const float*)d_in[16];
    const float* W_lin = (const float*)d_in[17];
    const float* b_lin = (const float*)d_in[18];
    float* out = (float*)d_out;

    const int NG_ = in_sizes[0] / 128;
    const int ND_ = in_sizes[1] / 128;
    const int EG_ = in_sizes[2];
    const int EDG_ = in_sizes[4];

    char* w = (char*)d_ws;
    auto alloc = [&](size_t bytes) -> char* {
        char* p = w;
        w += (bytes + 255) & ~(size_t)255;
        return p;
    };
    float* hg       = (float*)alloc((size_t)NG_ * 128 * 4);
    float* hd       = (float*)alloc((size_t)ND_ * 128 * 4);
    float* e_src_gg = (float*)alloc((size_t)NG_ * 8 * 4);
    float* e_dst_gg = (float*)alloc((size_t)NG_ * 8 * 4);
    float* e_dst_dg = (float*)alloc((size_t)NG_ * 8 * 4);
    float* e_src_dg = (float*)alloc((size_t)ND_ * 8 * 4);
    float* out_gg   = (float*)alloc((size_t)NG_ * 128 * 4);
    int* cnt   = (int*)alloc((size_t)(2 * NG_) * 4);      // [2N] combined counts
    int* offg  = (int*)alloc((size_t)(NG_ + 1) * 4);
    int* offd  = (int*)alloc((size_t)(NG_ + 1) * 4);
    int* rung  = (int*)alloc((size_t)NG_ * 4);
    int* rund  = (int*)alloc((size_t)NG_ * 4);
    int* srcs_g = (int*)alloc((size_t)EG_ * 4);
    int* srcs_d = (int*)alloc((size_t)EDG_ * 4);
    int* bsum  = (int*)alloc(8192);
    int* boff  = (int*)alloc(8192);
    float* score = (float*)alloc(1024);
    float* out_dg = hg;  // hg is dead after the gg aggregation; alias to save 51 MB

    const int N2 = 2 * NG_;
    const int nb2 = (N2 + 255) / 256;   // 782 <= 1024, fits single-block scan_bsum

    // 1. projections (+ e-vectors)
    proj_kernel<<<(NG_ + 31) / 32, 256, 0, stream>>>(
        x_gene, W_gene, b_gene, hg, NG_,
        att_src_gg, e_src_gg, att_dst_gg, e_dst_gg, att_dst_dg, e_dst_dg);
    proj_kernel<<<(ND_ + 31) / 32, 256, 0, stream>>>(
        x_dis, W_dis, b_dis, hd, ND_,
        att_src_dg, e_src_dg, (const float*)nullptr, (float*)nullptr,
        (const float*)nullptr, (float*)nullptr);

    // 2. fused CSR build (both graphs)
    hipMemsetAsync(cnt, 0, (size_t)N2 * 4, stream);
    hist2_kernel<<<(EG_ + EDG_ + 255) / 256, 256, 0, stream>>>(
        eg_dst, EG_, edg_dst, EDG_, cnt, NG_);
    scan_block_reduce<<<nb2, 256, 0, stream>>>(cnt, N2, bsum);
    scan_bsum<<<1, 1024, 0, stream>>>(bsum, nb2, boff);
    scan_final2<<<nb2, 256, 0, stream>>>(cnt, NG_, boff, EG_, EDG_, offg, offd, rung, rund);
    scatter2_kernel<<<(EG_ + EDG_ + 255) / 256, 256, 0, stream>>>(
        eg_dst, eg_src, EG_, edg_dst, edg_src, EDG_, rung, rund, srcs_g, srcs_d);

    // 3. aggregates (sequential: out_dg aliases hg, which gg-aggregate reads)
    aggregate_kernel<<<(NG_ + 3) / 4, 256, 0, stream>>>(
        hg, e_src_gg, e_dst_gg, offg, srcs_g, out_gg, NG_);
    aggregate_kernel<<<(NG_ + 3) / 4, 256, 0, stream>>>(
        hd, e_src_dg, e_dst_dg, offd, srcs_d, out_dg, NG_);

    // 4. fused semantic attention scores (both metapaths, one pass) + beta
    hipMemsetAsync(score, 0, 512, stream);
    score2_kernel<<<(NG_ + 15) / 16, 256, 0, stream>>>(out_gg, out_dg, Wk, bk, q, score, NG_);
    beta_kernel<<<1, 64, 0, stream>>>(score, 1.0f / (float)NG_);

    // 5. blend + final linear
    final_kernel<<<(NG_ + 31) / 32, 256, 0, stream>>>(
        out_gg, out_dg, score + 128, W_lin, b_lin, out, NG_);
}

// Round 10
// 429.345 us; speedup vs baseline: 1.4967x; 1.3219x over previous
//
#include <hip/hip_runtime.h>
#include <cstdint>
#include <cstddef>

#define NEG_SLOPE 0.2f
#define BSHIFT 8          // coarse bucket = dst >> 8 (256 dst nodes / bucket)

__device__ __forceinline__ float leakyf(float x) { return x > 0.f ? x : NEG_SLOPE * x; }
__device__ __forceinline__ float fast_tanh(float x) {
    float e = __expf(2.f * x);
    return 1.f - 2.f / (e + 1.f);
}

// ---------------- projection (x@W+b) + per-head attention dots ----------------
// block 256 = 8 row-groups x 32 col-threads; 32 rows/block, thread = 4 rows x 4 contiguous cols.
// W staged in LDS by 32-row K-chunks (synchronous barrier-staged copy — reg-dbuf variant
// REGRESSED in round 8; compiler schedules the simple copy better).
__global__ __launch_bounds__(256) void proj_kernel(
    const float* __restrict__ x, const float* __restrict__ W, const float* __restrict__ bias,
    float* __restrict__ hout, int N,
    const float* __restrict__ att0, float* __restrict__ e0,
    const float* __restrict__ att1, float* __restrict__ e1,
    const float* __restrict__ att2, float* __restrict__ e2)
{
    __shared__ float xlds[32 * 128];  // 16 KB: x tile
    __shared__ float wlds[32 * 128];  // 16 KB: W K-chunk
    const int t = threadIdx.x;
    const int row0 = blockIdx.x * 32;
    #pragma unroll
    for (int p = 0; p < 4; ++p) {
        int idx = t + 256 * p;
        int r = idx >> 5;
        int c4 = idx & 31;
        float4 v = make_float4(0.f, 0.f, 0.f, 0.f);
        if (row0 + r < N) v = *(const float4*)(x + (size_t)(row0 + r) * 128 + c4 * 4);
        *(float4*)(xlds + r * 128 + c4 * 4) = v;
    }
    const int rg = t >> 5, ct = t & 31;
    float acc[4][4];
    {
        float4 bv = *(const float4*)(bias + ct * 4);
        #pragma unroll
        for (int rr = 0; rr < 4; ++rr) {
            acc[rr][0] = bv.x; acc[rr][1] = bv.y; acc[rr][2] = bv.z; acc[rr][3] = bv.w;
        }
    }
    for (int kc = 0; kc < 4; ++kc) {
        __syncthreads();  // kc=0: x staged; kc>0: previous chunk's compute done (WAR on wlds)
        #pragma unroll
        for (int p = 0; p < 4; ++p) {
            int idx = t + 256 * p;
            *(float4*)(wlds + idx * 4) = *(const float4*)(W + (size_t)kc * 4096 + idx * 4);
        }
        __syncthreads();
        #pragma unroll 2
        for (int i2 = 0; i2 < 32; i2 += 4) {
            const int i = kc * 32 + i2;
            float4 xv[4];
            #pragma unroll
            for (int rr = 0; rr < 4; ++rr) xv[rr] = *(const float4*)(xlds + (rg + 8 * rr) * 128 + i);
            #pragma unroll
            for (int qq = 0; qq < 4; ++qq) {
                float4 wv = *(const float4*)(wlds + (i2 + qq) * 128 + ct * 4);
                #pragma unroll
                for (int rr = 0; rr < 4; ++rr) {
                    float xs = ((const float*)&xv[rr])[qq];
                    acc[rr][0] = fmaf(xs, wv.x, acc[rr][0]);
                    acc[rr][1] = fmaf(xs, wv.y, acc[rr][1]);
                    acc[rr][2] = fmaf(xs, wv.z, acc[rr][2]);
                    acc[rr][3] = fmaf(xs, wv.w, acc[rr][3]);
                }
            }
        }
    }
    // store h
    #pragma unroll
    for (int rr = 0; rr < 4; ++rr) {
        int grow = row0 + rg + 8 * rr;
        if (grow < N)
            *(float4*)(hout + (size_t)grow * 128 + ct * 4) =
                make_float4(acc[rr][0], acc[rr][1], acc[rr][2], acc[rr][3]);
    }
    // e-dots: thread's 4 cols are inside head (ct>>2); reduce over 4-lane col group
    const int head = ct >> 2;
    const bool wlane = (ct & 3) == 0;
    if (att0) {
        float4 av = *(const float4*)(att0 + ct * 4);
        #pragma unroll
        for (int rr = 0; rr < 4; ++rr) {
            float p_ = acc[rr][0] * av.x + acc[rr][1] * av.y + acc[rr][2] * av.z + acc[rr][3] * av.w;
            p_ += __shfl_xor(p_, 1);
            p_ += __shfl_xor(p_, 2);
            int grow = row0 + rg + 8 * rr;
            if (wlane && grow < N) e0[(size_t)grow * 8 + head] = p_;
        }
    }
    if (att1) {
        float4 av = *(const float4*)(att1 + ct * 4);
        #pragma unroll
        for (int rr = 0; rr < 4; ++rr) {
            float p_ = acc[rr][0] * av.x + acc[rr][1] * av.y + acc[rr][2] * av.z + acc[rr][3] * av.w;
            p_ += __shfl_xor(p_, 1);
            p_ += __shfl_xor(p_, 2);
            int grow = row0 + rg + 8 * rr;
            if (wlane && grow < N) e1[(size_t)grow * 8 + head] = p_;
        }
    }
    if (att2) {
        float4 av = *(const float4*)(att2 + ct * 4);
        #pragma unroll
        for (int rr = 0; rr < 4; ++rr) {
            float p_ = acc[rr][0] * av.x + acc[rr][1] * av.y + acc[rr][2] * av.z + acc[rr][3] * av.w;
            p_ += __shfl_xor(p_, 1);
            p_ += __shfl_xor(p_, 2);
            int grow = row0 + rg + 8 * rr;
            if (wlane && grow < N) e2[(size_t)grow * 8 + head] = p_;
        }
    }
}

// ================= two-level bucket CSR build =================
// Replaces direct scatter (109 MB of 64B-line writebacks for 6.4 MB payload, round-9 PMC).
// Coarse bucket = dst>>8. Buckets [0,NBg) = gene graph, [NBg, 2*NBg) = disease graph.
// coarse[] entries pack src (24 bits) | (dst&255) << 24.

// per-block LDS histogram of bucket counts, one global flush per block
__global__ __launch_bounds__(256) void bucket_hist(
    const int* __restrict__ dstg, int Eg, const int* __restrict__ dstd, int Ed,
    int NBg, int NBtot, int* __restrict__ bucketCnt)
{
    __shared__ int h[1024];
    const int t = threadIdx.x;
    for (int j = t; j < NBtot; j += 256) h[j] = 0;
    __syncthreads();
    const int Etot = Eg + Ed;
    const int base = blockIdx.x * 4096;
    #pragma unroll
    for (int k = 0; k < 16; ++k) {
        int i = base + k * 256 + t;
        if (i < Etot) {
            int b = (i < Eg) ? (dstg[i] >> BSHIFT) : NBg + (dstd[i - Eg] >> BSHIFT);
            atomicAdd(&h[b], 1);
        }
    }
    __syncthreads();
    for (int j = t; j < NBtot; j += 256) {
        int c = h[j];
        if (c) atomicAdd(&bucketCnt[j], c);
    }
}

// single-block exclusive scan of bucket counts -> base + cursor
__global__ void bucket_scan(const int* __restrict__ bucketCnt, int NBtot, int Etot,
                            int* __restrict__ bucketBase, int* __restrict__ bucketCursor)
{
    __shared__ int s[1024];
    int t = threadIdx.x;
    int v = (t < NBtot) ? bucketCnt[t] : 0;
    s[t] = v;
    __syncthreads();
    for (int o = 1; o < 1024; o <<= 1) {
        int add = (t >= o) ? s[t - o] : 0;
        __syncthreads();
        s[t] += add;
        __syncthreads();
    }
    if (t < NBtot) {
        int e = s[t] - v;
        bucketBase[t] = e;
        bucketCursor[t] = e;
    }
    if (t == 0) bucketBase[NBtot] = Etot;
}

// block-aggregated scatter into coarse buckets: one ranged atomic per (block,bucket),
// contiguous runs -> ~12 B/edge writeback instead of 64.
__global__ __launch_bounds__(256) void bucket_scatter(
    const int* __restrict__ dstg, const int* __restrict__ srcg, int Eg,
    const int* __restrict__ dstd, const int* __restrict__ srcd, int Ed,
    int NBg, int NBtot, int* __restrict__ bucketCursor, unsigned* __restrict__ coarse)
{
    __shared__ int h[800];
    __shared__ int basearr[800];
    __shared__ int cur[800];
    const int t = threadIdx.x;
    for (int j = t; j < NBtot; j += 256) h[j] = 0;
    __syncthreads();
    const int Etot = Eg + Ed;
    const int base = blockIdx.x * 4096;
    int bk[16];
    unsigned pk[16];
    #pragma unroll
    for (int k = 0; k < 16; ++k) {
        int i = base + k * 256 + t;
        bk[k] = -1;
        if (i < Etot) {
            int dst, src, goff;
            if (i < Eg) { dst = dstg[i]; src = srcg[i]; goff = 0; }
            else        { dst = dstd[i - Eg]; src = srcd[i - Eg]; goff = NBg; }
            bk[k] = goff + (dst >> BSHIFT);
            pk[k] = (unsigned)src | ((unsigned)(dst & 255) << 24);
            atomicAdd(&h[bk[k]], 1);
        }
    }
    __syncthreads();
    for (int j = t; j < NBtot; j += 256) {
        int c = h[j];
        basearr[j] = c ? atomicAdd(&bucketCursor[j], c) : 0;
        cur[j] = 0;
    }
    __syncthreads();
    #pragma unroll
    for (int k = 0; k < 16; ++k) {
        if (bk[k] >= 0) {
            int r = atomicAdd(&cur[bk[k]], 1);
            coarse[basearr[bk[k]] + r] = pk[k];
        }
    }
}

// one block per bucket: LDS 256-bin histogram + scan -> off[] (coalesced) and
// final src placement into a contiguous ~8 KB region (L2-friendly writes).
__global__ __launch_bounds__(256) void bucket_sort(
    const unsigned* __restrict__ coarse, const int* __restrict__ bucketBase,
    int NBg, int Eg, int Ed, int N,
    int* __restrict__ offg, int* __restrict__ offd,
    int* __restrict__ srcs_g, int* __restrict__ srcs_d)
{
    __shared__ int hist[256];
    __shared__ int excl[256];
    __shared__ int cur[256];
    const int b = blockIdx.x;
    const int t = threadIdx.x;
    const int s0 = bucketBase[b], s1 = bucketBase[b + 1];
    const int cnt = s1 - s0;
    const bool isg = b < NBg;
    const int d0 = (isg ? b : b - NBg) << BSHIFT;
    hist[t] = 0;
    __syncthreads();
    for (int i = t; i < cnt; i += 256) {
        unsigned p = coarse[s0 + i];
        atomicAdd(&hist[p >> 24], 1);
    }
    __syncthreads();
    int v = hist[t];
    excl[t] = v;
    __syncthreads();
    for (int o = 1; o < 256; o <<= 1) {
        int add = (t >= o) ? excl[t - o] : 0;
        __syncthreads();
        excl[t] += add;
        __syncthreads();
    }
    const int e = excl[t] - v;  // exclusive prefix within bucket
    const int localBase = isg ? s0 : s0 - Eg;
    const int d = d0 + t;
    if (d < N) {
        if (isg) offg[d] = localBase + e;
        else     offd[d] = localBase + e;
    }
    cur[t] = e;
    __syncthreads();
    int* outp = isg ? srcs_g : srcs_d;
    for (int i = t; i < cnt; i += 256) {
        unsigned p = coarse[s0 + i];
        int r = atomicAdd(&cur[p >> 24], 1);
        outp[localBase + r] = (int)(p & 0xFFFFFFu);
    }
    if (b == 0 && t == 0) { offg[N] = Eg; offd[N] = Ed; }
}

// ---------------- per-dst-node softmax aggregation (1 wave per node) ----------------
__global__ __launch_bounds__(256) void aggregate_kernel(
    const float* __restrict__ xs,        // [Ns,128] projected src feats
    const float* __restrict__ esrc,      // [Ns,8]
    const float* __restrict__ edst,      // [Nd,8]
    const int* __restrict__ off,         // [Nd+1]
    const int* __restrict__ srcsorted,   // [E] src ids bucketed by dst
    float* __restrict__ outp,            // [Nd,128]
    int Nd)
{
    __shared__ float exbuf[4][64 * 8];
    const int lane = threadIdx.x & 63;
    const int wslot = threadIdx.x >> 6;
    const int n = blockIdx.x * 4 + wslot;
    if (n >= Nd) return;
    const int o0 = off[n], o1 = off[n + 1];
    const int deg = o1 - o0;
    const int li = lane & 31, half = lane >> 5;
    const int j0 = li * 4;       // this lane's 4 cols (within its half)
    const int hh = li >> 2;      // head owning those cols
    if (deg == 0) {
        if (half == 0) *(float4*)(outp + (size_t)n * 128 + j0) = make_float4(0.f, 0.f, 0.f, 0.f);
        return;
    }
    float ed[8];
    {
        float4 a = *(const float4*)(edst + (size_t)n * 8);
        float4 b = *(const float4*)(edst + (size_t)n * 8 + 4);
        ed[0] = a.x; ed[1] = a.y; ed[2] = a.z; ed[3] = a.w;
        ed[4] = b.x; ed[5] = b.y; ed[6] = b.z; ed[7] = b.w;
    }
    if (deg <= 64) {
        const bool act = lane < deg;
        int s = act ? srcsorted[o0 + lane] : 0;   // coalesced
        float m[8];
        {
            float4 ea = make_float4(0.f, 0.f, 0.f, 0.f), eb = ea;
            if (act) {
                ea = *(const float4*)(esrc + (size_t)s * 8);
                eb = *(const float4*)(esrc + (size_t)s * 8 + 4);
            }
            float a[8] = {ea.x, ea.y, ea.z, ea.w, eb.x, eb.y, eb.z, eb.w};
            #pragma unroll
            for (int h2 = 0; h2 < 8; ++h2) m[h2] = act ? leakyf(a[h2] + ed[h2]) : -1e30f;
        }
        float al[8];
        #pragma unroll
        for (int h2 = 0; h2 < 8; ++h2) al[h2] = m[h2];
        for (int o = 1; o < deg; o <<= 1) {
            #pragma unroll
            for (int h2 = 0; h2 < 8; ++h2) m[h2] = fmaxf(m[h2], __shfl_xor(m[h2], o));
        }
        float exv[8];
        #pragma unroll
        for (int h2 = 0; h2 < 8; ++h2) exv[h2] = act ? __expf(al[h2] - m[h2]) : 0.f;
        *(float4*)(&exbuf[wslot][lane * 8])     = make_float4(exv[0], exv[1], exv[2], exv[3]);
        *(float4*)(&exbuf[wslot][lane * 8 + 4]) = make_float4(exv[4], exv[5], exv[6], exv[7]);
        float4 num = make_float4(0.f, 0.f, 0.f, 0.f);
        float den = 0.f;
        const int iters = (deg + 1) >> 1;
        #pragma unroll 2
        for (int k = 0; k < iters; ++k) {
            int i = 2 * k + half;
            if (i < deg) {
                int si = __shfl(s, i);
                float wgt = exbuf[wslot][i * 8 + hh];
                float4 xv = *(const float4*)(xs + (size_t)si * 128 + j0);
                num.x = fmaf(wgt, xv.x, num.x);
                num.y = fmaf(wgt, xv.y, num.y);
                num.z = fmaf(wgt, xv.z, num.z);
                num.w = fmaf(wgt, xv.w, num.w);
                den += wgt;
            }
        }
        num.x += __shfl_xor(num.x, 32);
        num.y += __shfl_xor(num.y, 32);
        num.z += __shfl_xor(num.z, 32);
        num.w += __shfl_xor(num.w, 32);
        den += __shfl_xor(den, 32);
        if (half == 0) {
            float inv = 1.f / (den + 1e-16f);
            float4 r;
            r.x = fmaxf(num.x * inv, 0.f);
            r.y = fmaxf(num.y * inv, 0.f);
            r.z = fmaxf(num.z * inv, 0.f);
            r.w = fmaxf(num.w * inv, 0.f);
            *(float4*)(outp + (size_t)n * 128 + j0) = r;
        }
        return;
    }
    // ---- slow path (deg > 64) ----
    {
        const int j0b = lane * 2;
        const int h = lane >> 3;
        float m[8];
        #pragma unroll
        for (int hh2 = 0; hh2 < 8; ++hh2) m[hh2] = -1e30f;
        for (int base = 0; base < deg; base += 64) {
            int ii = base + lane;
            bool act = ii < deg;
            int s = srcsorted[o0 + (act ? ii : 0)];
            float4 ea = *(const float4*)(esrc + (size_t)s * 8);
            float4 eb = *(const float4*)(esrc + (size_t)s * 8 + 4);
            float a[8] = {ea.x, ea.y, ea.z, ea.w, eb.x, eb.y, eb.z, eb.w};
            #pragma unroll
            for (int hh2 = 0; hh2 < 8; ++hh2) {
                float v = act ? leakyf(a[hh2] + ed[hh2]) : -1e30f;
                #pragma unroll
                for (int o = 1; o < 64; o <<= 1) v = fmaxf(v, __shfl_xor(v, o));
                m[hh2] = fmaxf(m[hh2], v);
            }
        }
        float mh, edh;
        {
            float t4a = (h & 4) ? m[4] : m[0];
            float t4b = (h & 4) ? m[5] : m[1];
            float t4c = (h & 4) ? m[6] : m[2];
            float t4d = (h & 4) ? m[7] : m[3];
            float t2a = (h & 2) ? t4c : t4a;
            float t2b = (h & 2) ? t4d : t4b;
            mh = (h & 1) ? t2b : t2a;
            float u4a = (h & 4) ? ed[4] : ed[0];
            float u4b = (h & 4) ? ed[5] : ed[1];
            float u4c = (h & 4) ? ed[6] : ed[2];
            float u4d = (h & 4) ? ed[7] : ed[3];
            float u2a = (h & 2) ? u4c : u4a;
            float u2b = (h & 2) ? u4d : u4b;
            edh = (h & 1) ? u2b : u2a;
        }
        float den = 0.f, num0 = 0.f, num1 = 0.f;
        for (int base = 0; base < deg; base += 64) {
            int ii = base + lane;
            bool act = ii < deg;
            int sreg = srcsorted[o0 + (act ? ii : 0)];
            int cl = deg - base;
            if (cl > 64) cl = 64;
            for (int i = 0; i < cl; ++i) {
                int s = __shfl(sreg, i);
                float ev = esrc[(size_t)s * 8 + h];
                float ex = __expf(leakyf(ev + edh) - mh);
                float2 xv = *(const float2*)(xs + (size_t)s * 128 + j0b);
                num0 = fmaf(ex, xv.x, num0);
                num1 = fmaf(ex, xv.y, num1);
                den += ex;
            }
        }
        float inv = 1.f / (den + 1e-16f);
        float r0 = num0 * inv, r1 = num1 * inv;
        r0 = r0 > 0.f ? r0 : 0.f;
        r1 = r1 > 0.f ? r1 : 0.f;
        *(float2*)(outp + (size_t)n * 128 + j0b) = make_float2(r0, r1);
    }
}

// ---------------- fused semantic attention scores for BOTH metapaths ----------------
// Half-tile packing (16 gg rows + 16 dg rows per 32x128 tile) for occupancy; Wk staged in
// LDS by synchronous K-chunks (round-7 proven version).
__global__ __launch_bounds__(256) void score2_kernel(
    const float* __restrict__ gg, const float* __restrict__ dg,
    const float* __restrict__ Wk, const float* __restrict__ bk, const float* __restrict__ q,
    float* __restrict__ scoreAcc, int N)
{
    __shared__ float tile[32 * 128];
    __shared__ float wlds[32 * 128];
    __shared__ float sred[8];
    const int t = threadIdx.x;
    const int row0 = blockIdx.x * 16;
    #pragma unroll
    for (int p = 0; p < 4; ++p) {
        int idx = t + 256 * p;
        int r = idx >> 5;
        int c4 = idx & 31;
        int gr = row0 + (r & 15);
        const float* srcp = (r < 16) ? gg : dg;
        float4 v = make_float4(0.f, 0.f, 0.f, 0.f);
        if (gr < N) v = *(const float4*)(srcp + (size_t)gr * 128 + c4 * 4);
        *(float4*)(tile + r * 128 + c4 * 4) = v;
    }
    const int rg = t >> 5, ct = t & 31;
    float acc[4][4];
    {
        float4 bv = *(const float4*)(bk + ct * 4);
        #pragma unroll
        for (int rr = 0; rr < 4; ++rr) {
            acc[rr][0] = bv.x; acc[rr][1] = bv.y; acc[rr][2] = bv.z; acc[rr][3] = bv.w;
        }
    }
    for (int kc = 0; kc < 4; ++kc) {
        __syncthreads();
        #pragma unroll
        for (int p = 0; p < 4; ++p) {
            int idx = t + 256 * p;
            *(float4*)(wlds + idx * 4) = *(const float4*)(Wk + (size_t)kc * 4096 + idx * 4);
        }
        __syncthreads();
        #pragma unroll 2
        for (int i2 = 0; i2 < 32; i2 += 4) {
            const int i = kc * 32 + i2;
            float4 xv[4];
            #pragma unroll
            for (int rr = 0; rr < 4; ++rr) xv[rr] = *(const float4*)(tile + (rg + 8 * rr) * 128 + i);
            #pragma unroll
            for (int qq = 0; qq < 4; ++qq) {
                float4 wv = *(const float4*)(wlds + (i2 + qq) * 128 + ct * 4);
                #pragma unroll
                for (int rr = 0; rr < 4; ++rr) {
                    float xs = ((const float*)&xv[rr])[qq];
                    acc[rr][0] = fmaf(xs, wv.x, acc[rr][0]);
                    acc[rr][1] = fmaf(xs, wv.y, acc[rr][1]);
                    acc[rr][2] = fmaf(xs, wv.z, acc[rr][2]);
                    acc[rr][3] = fmaf(xs, wv.w, acc[rr][3]);
                }
            }
        }
    }
    float4 qv = *(const float4*)(q + ct * 4);
    float pg = 0.f, pd = 0.f;
    #pragma unroll
    for (int rr = 0; rr < 4; ++rr) {
        int r = rg + 8 * rr;               // tile row
        int grow = row0 + (r & 15);        // global row
        if (grow < N) {
            float p_ = 0.f;
            p_ = fmaf(fast_tanh(acc[rr][0]), qv.x, p_);
            p_ = fmaf(fast_tanh(acc[rr][1]), qv.y, p_);
            p_ = fmaf(fast_tanh(acc[rr][2]), qv.z, p_);
            p_ = fmaf(fast_tanh(acc[rr][3]), qv.w, p_);
            if (r < 16) pg += p_; else pd += p_;
        }
    }
    #pragma unroll
    for (int o = 1; o < 64; o <<= 1) {
        pg += __shfl_xor(pg, o);
        pd += __shfl_xor(pd, o);
    }
    if ((t & 63) == 0) {
        sred[(t >> 6) * 2] = pg;
        sred[(t >> 6) * 2 + 1] = pd;
    }
    __syncthreads();
    if (t == 0) {
        float sg = sred[0] + sred[2] + sred[4] + sred[6];
        float sd = sred[1] + sred[3] + sred[5] + sred[7];
        int slot = blockIdx.x & 63;
        atomicAdd(&scoreAcc[slot], sg);
        atomicAdd(&scoreAcc[64 + slot], sd);
    }
}

// ---------------- tiny: reduce 2x64 score slots -> softmax betas ----------------
__global__ void beta_kernel(float* __restrict__ scoreAcc, float invN) {
    int t = threadIdx.x;  // 64 threads
    float v0 = scoreAcc[t];
    float v1 = scoreAcc[64 + t];
    #pragma unroll
    for (int o = 1; o < 64; o <<= 1) {
        v0 += __shfl_xor(v0, o);
        v1 += __shfl_xor(v1, o);
    }
    if (t == 0) {
        float s0 = v0 * invN, s1 = v1 * invN;
        float mx = fmaxf(s0, s1);
        float e0 = __expf(s0 - mx), e1 = __expf(s1 - mx);
        float inv = 1.f / (e0 + e1);
        scoreAcc[128] = e0 * inv;
        scoreAcc[129] = e1 * inv;
    }
}

// ---------------- final: beta blend + @W_lin + b_lin (W_lin staged in LDS) ----------------
__global__ __launch_bounds__(256) void final_kernel(
    const float* __restrict__ gg, const float* __restrict__ dg,
    const float* __restrict__ beta,   // scoreAcc+128: {beta0, beta1}
    const float* __restrict__ Wl, const float* __restrict__ bl,
    float* __restrict__ outp, int N)
{
    __shared__ float wlds[128 * 64];  // 32 KB — whole W_lin
    __shared__ float glds[32 * 128];  // 16 KB — blended tile
    const int t = threadIdx.x;
    #pragma unroll
    for (int p = 0; p < 8; ++p) {
        int idx = (t + 256 * p) * 4;
        *(float4*)(wlds + idx) = *(const float4*)(Wl + idx);
    }
    const float bet0 = beta[0], bet1 = beta[1];
    const int row0 = blockIdx.x * 32;
    #pragma unroll
    for (int p = 0; p < 4; ++p) {
        int idx = t + 256 * p;
        int r = idx >> 5;
        int c4 = idx & 31;
        float4 a = make_float4(0.f, 0.f, 0.f, 0.f), b = a, g;
        if (row0 + r < N) {
            a = *(const float4*)(gg + (size_t)(row0 + r) * 128 + c4 * 4);
            b = *(const float4*)(dg + (size_t)(row0 + r) * 128 + c4 * 4);
        }
        g.x = bet0 * a.x + bet1 * b.x;
        g.y = bet0 * a.y + bet1 * b.y;
        g.z = bet0 * a.z + bet1 * b.z;
        g.w = bet0 * a.w + bet1 * b.w;
        *(float4*)(glds + r * 128 + c4 * 4) = g;
    }
    __syncthreads();
    const int rg = t >> 5, ct = t & 31;
    float acc[4][2];
    {
        float2 bv = *(const float2*)(bl + ct * 2);
        #pragma unroll
        for (int rr = 0; rr < 4; ++rr) { acc[rr][0] = bv.x; acc[rr][1] = bv.y; }
    }
    #pragma unroll 2
    for (int i = 0; i < 128; i += 4) {
        float4 xv[4];
        #pragma unroll
        for (int rr = 0; rr < 4; ++rr) xv[rr] = *(const float4*)(glds + (rg + 8 * rr) * 128 + i);
        #pragma unroll
        for (int qq = 0; qq < 4; ++qq) {
            float2 wv = *(const float2*)(wlds + (i + qq) * 64 + ct * 2);
            #pragma unroll
            for (int rr = 0; rr < 4; ++rr) {
                float xs = ((const float*)&xv[rr])[qq];
                acc[rr][0] = fmaf(xs, wv.x, acc[rr][0]);
                acc[rr][1] = fmaf(xs, wv.y, acc[rr][1]);
            }
        }
    }
    #pragma unroll
    for (int rr = 0; rr < 4; ++rr) {
        int grow = row0 + rg + 8 * rr;
        if (grow < N)
            *(float2*)(outp + (size_t)grow * 64 + ct * 2) = make_float2(acc[rr][0], acc[rr][1]);
    }
}

extern "C" void kernel_launch(void* const* d_in, const int* in_sizes, int n_in,
                              void* d_out, int out_size, void* d_ws, size_t ws_size,
                              hipStream_t stream) {
    (void)n_in; (void)out_size; (void)ws_size;
    const float* x_gene = (const float*)d_in[0];
    const float* x_dis  = (const float*)d_in[1];
    const int* eg_src   = (const int*)d_in[2];
    const int* eg_dst   = (const int*)d_in[3];
    const int* edg_src  = (const int*)d_in[4];
    const int* edg_dst  = (const int*)d_in[5];
    const float* W_gene = (const float*)d_in[6];
    const float* b_gene = (const float*)d_in[7];
    const float* W_dis  = (const float*)d_in[8];
    const float* b_dis  = (const float*)d_in[9];
    const float* att_src_gg = (const float*)d_in[10];
    const float* att_dst_gg = (const float*)d_in[11];
    const float* att_src_dg = (const float*)d_in[12];
    const float* att_dst_dg = (const float*)d_in[13];
    const float* Wk    = (const float*)d_in[14];
    const float* bk    = (const float*)d_in[15];
    const float* q     = (const float*)d_in[16];
    const float* W_lin = (const float*)d_in[17];
    const float* b_lin = (const float*)d_in[18];
    float* out = (float*)d_out;

    const int NG_ = in_sizes[0] / 128;
    const int ND_ = in_sizes[1] / 128;
    const int EG_ = in_sizes[2];
    const int EDG_ = in_sizes[4];

    char* w = (char*)d_ws;
    auto alloc = [&](size_t bytes) -> char* {
        char* p = w;
        w += (bytes + 255) & ~(size_t)255;
        return p;
    };
    float* hg       = (float*)alloc((size_t)NG_ * 128 * 4);
    float* hd       = (float*)alloc((size_t)ND_ * 128 * 4);
    float* e_src_gg = (float*)alloc((size_t)NG_ * 8 * 4);
    float* e_dst_gg = (float*)alloc((size_t)NG_ * 8 * 4);
    float* e_dst_dg = (float*)alloc((size_t)NG_ * 8 * 4);
    float* e_src_dg = (float*)alloc((size_t)ND_ * 8 * 4);
    float* out_gg   = (float*)alloc((size_t)NG_ * 128 * 4);
    int* offg  = (int*)alloc((size_t)(NG_ + 1) * 4);
    int* offd  = (int*)alloc((size_t)(NG_ + 1) * 4);
    int* srcs_g = (int*)alloc((size_t)EG_ * 4);
    int* srcs_d = (int*)alloc((size_t)EDG_ * 4);
    unsigned* coarse = (unsigned*)alloc((size_t)(EG_ + EDG_) * 4);
    int* bucketCnt    = (int*)alloc(4096);
    int* bucketBase   = (int*)alloc(4096);
    int* bucketCursor = (int*)alloc(4096);
    float* score = (float*)alloc(1024);
    float* out_dg = hg;  // hg is dead after the gg aggregation; alias to save 51 MB

    const int NBg = (NG_ + 255) >> BSHIFT;   // 391 for NG=100000
    const int NBtot = 2 * NBg;               // 782 <= 1024 (single-block scan) and <= 800 (LDS arrays)
    const int Etot = EG_ + EDG_;
    const int nbE = (Etot + 4095) / 4096;

    // 1. projections (+ e-vectors)
    proj_kernel<<<(NG_ + 31) / 32, 256, 0, stream>>>(
        x_gene, W_gene, b_gene, hg, NG_,
        att_src_gg, e_src_gg, att_dst_gg, e_dst_gg, att_dst_dg, e_dst_dg);
    proj_kernel<<<(ND_ + 31) / 32, 256, 0, stream>>>(
        x_dis, W_dis, b_dis, hd, ND_,
        att_src_dg, e_src_dg, (const float*)nullptr, (float*)nullptr,
        (const float*)nullptr, (float*)nullptr);

    // 2. two-level bucket CSR build (both graphs)
    hipMemsetAsync(bucketCnt, 0, (size_t)NBtot * 4, stream);
    bucket_hist<<<nbE, 256, 0, stream>>>(eg_dst, EG_, edg_dst, EDG_, NBg, NBtot, bucketCnt);
    bucket_scan<<<1, 1024, 0, stream>>>(bucketCnt, NBtot, Etot, bucketBase, bucketCursor);
    bucket_scatter<<<nbE, 256, 0, stream>>>(
        eg_dst, eg_src, EG_, edg_dst, edg_src, EDG_, NBg, NBtot, bucketCursor, coarse);
    bucket_sort<<<NBtot, 256, 0, stream>>>(
        coarse, bucketBase, NBg, EG_, EDG_, NG_, offg, offd, srcs_g, srcs_d);

    // 3. aggregates (sequential: out_dg aliases hg, which gg-aggregate reads)
    aggregate_kernel<<<(NG_ + 3) / 4, 256, 0, stream>>>(
        hg, e_src_gg, e_dst_gg, offg, srcs_g, out_gg, NG_);
    aggregate_kernel<<<(NG_ + 3) / 4, 256, 0, stream>>>(
        hd, e_src_dg, e_dst_dg, offd, srcs_d, out_dg, NG_);

    // 4. fused semantic attention scores (both metapaths, one pass) + beta
    hipMemsetAsync(score, 0, 512, stream);
    score2_kernel<<<(NG_ + 15) / 16, 256, 0, stream>>>(out_gg, out_dg, Wk, bk, q, score, NG_);
    beta_kernel<<<1, 64, 0, stream>>>(score, 1.0f / (float)NG_);

    // 5. blend + final linear
    final_kernel<<<(NG_ + 31) / 32, 256, 0, stream>>>(
        out_gg, out_dg, score + 128, W_lin, b_lin, out, NG_);
}

// Round 11
// 426.952 us; speedup vs baseline: 1.5051x; 1.0056x over previous
//
#include <hip/hip_runtime.h>
#include <cstdint>
#include <cstddef>

#define NEG_SLOPE 0.2f
#define BSHIFT 8          // coarse bucket = dst >> 8 (256 dst nodes / bucket)

__device__ __forceinline__ float leakyf(float x) { return x > 0.f ? x : NEG_SLOPE * x; }
__device__ __forceinline__ float fast_tanh(float x) {
    float e = __expf(2.f * x);
    return 1.f - 2.f / (e + 1.f);
}

// ---------------- projection (x@W+b) + per-head attention dots ----------------
// block 256 = 8 row-groups x 32 col-threads; 32 rows/block, thread = 4 rows x 4 contiguous cols.
// W staged in LDS by 16-row K-chunks (8 KB) -> LDS total 24.3 KB -> 6 blocks/CU
// (32-row chunks gave 4 blocks/CU, occupancy 37%, VALUBusy 67% — round-10 PMC).
__global__ __launch_bounds__(256) void proj_kernel(
    const float* __restrict__ x, const float* __restrict__ W, const float* __restrict__ bias,
    float* __restrict__ hout, int N,
    const float* __restrict__ att0, float* __restrict__ e0,
    const float* __restrict__ att1, float* __restrict__ e1,
    const float* __restrict__ att2, float* __restrict__ e2)
{
    __shared__ float xlds[32 * 128];  // 16 KB: x tile
    __shared__ float wlds[16 * 128];  // 8 KB: W K-chunk
    const int t = threadIdx.x;
    const int row0 = blockIdx.x * 32;
    #pragma unroll
    for (int p = 0; p < 4; ++p) {
        int idx = t + 256 * p;
        int r = idx >> 5;
        int c4 = idx & 31;
        float4 v = make_float4(0.f, 0.f, 0.f, 0.f);
        if (row0 + r < N) v = *(const float4*)(x + (size_t)(row0 + r) * 128 + c4 * 4);
        *(float4*)(xlds + r * 128 + c4 * 4) = v;
    }
    const int rg = t >> 5, ct = t & 31;
    float acc[4][4];
    {
        float4 bv = *(const float4*)(bias + ct * 4);
        #pragma unroll
        for (int rr = 0; rr < 4; ++rr) {
            acc[rr][0] = bv.x; acc[rr][1] = bv.y; acc[rr][2] = bv.z; acc[rr][3] = bv.w;
        }
    }
    for (int kc = 0; kc < 8; ++kc) {
        __syncthreads();  // kc=0: x staged; kc>0: previous chunk's compute done (WAR on wlds)
        #pragma unroll
        for (int p = 0; p < 2; ++p) {
            int idx = t + 256 * p;
            *(float4*)(wlds + idx * 4) = *(const float4*)(W + (size_t)kc * 2048 + idx * 4);
        }
        __syncthreads();
        #pragma unroll 2
        for (int i2 = 0; i2 < 16; i2 += 4) {
            const int i = kc * 16 + i2;
            float4 xv[4];
            #pragma unroll
            for (int rr = 0; rr < 4; ++rr) xv[rr] = *(const float4*)(xlds + (rg + 8 * rr) * 128 + i);
            #pragma unroll
            for (int qq = 0; qq < 4; ++qq) {
                float4 wv = *(const float4*)(wlds + (i2 + qq) * 128 + ct * 4);
                #pragma unroll
                for (int rr = 0; rr < 4; ++rr) {
                    float xs = ((const float*)&xv[rr])[qq];
                    acc[rr][0] = fmaf(xs, wv.x, acc[rr][0]);
                    acc[rr][1] = fmaf(xs, wv.y, acc[rr][1]);
                    acc[rr][2] = fmaf(xs, wv.z, acc[rr][2]);
                    acc[rr][3] = fmaf(xs, wv.w, acc[rr][3]);
                }
            }
        }
    }
    // store h
    #pragma unroll
    for (int rr = 0; rr < 4; ++rr) {
        int grow = row0 + rg + 8 * rr;
        if (grow < N)
            *(float4*)(hout + (size_t)grow * 128 + ct * 4) =
                make_float4(acc[rr][0], acc[rr][1], acc[rr][2], acc[rr][3]);
    }
    // e-dots: thread's 4 cols are inside head (ct>>2); reduce over 4-lane col group
    const int head = ct >> 2;
    const bool wlane = (ct & 3) == 0;
    if (att0) {
        float4 av = *(const float4*)(att0 + ct * 4);
        #pragma unroll
        for (int rr = 0; rr < 4; ++rr) {
            float p_ = acc[rr][0] * av.x + acc[rr][1] * av.y + acc[rr][2] * av.z + acc[rr][3] * av.w;
            p_ += __shfl_xor(p_, 1);
            p_ += __shfl_xor(p_, 2);
            int grow = row0 + rg + 8 * rr;
            if (wlane && grow < N) e0[(size_t)grow * 8 + head] = p_;
        }
    }
    if (att1) {
        float4 av = *(const float4*)(att1 + ct * 4);
        #pragma unroll
        for (int rr = 0; rr < 4; ++rr) {
            float p_ = acc[rr][0] * av.x + acc[rr][1] * av.y + acc[rr][2] * av.z + acc[rr][3] * av.w;
            p_ += __shfl_xor(p_, 1);
            p_ += __shfl_xor(p_, 2);
            int grow = row0 + rg + 8 * rr;
            if (wlane && grow < N) e1[(size_t)grow * 8 + head] = p_;
        }
    }
    if (att2) {
        float4 av = *(const float4*)(att2 + ct * 4);
        #pragma unroll
        for (int rr = 0; rr < 4; ++rr) {
            float p_ = acc[rr][0] * av.x + acc[rr][1] * av.y + acc[rr][2] * av.z + acc[rr][3] * av.w;
            p_ += __shfl_xor(p_, 1);
            p_ += __shfl_xor(p_, 2);
            int grow = row0 + rg + 8 * rr;
            if (wlane && grow < N) e2[(size_t)grow * 8 + head] = p_;
        }
    }
}

// ================= two-level bucket CSR build =================
// Coarse bucket = dst>>8. Buckets [0,NBg) = gene graph, [NBg, 2*NBg) = disease graph.
// coarse[] entries pack src (24 bits) | (dst&255) << 24.

__global__ __launch_bounds__(256) void bucket_hist(
    const int* __restrict__ dstg, int Eg, const int* __restrict__ dstd, int Ed,
    int NBg, int NBtot, int* __restrict__ bucketCnt)
{
    __shared__ int h[1024];
    const int t = threadIdx.x;
    for (int j = t; j < NBtot; j += 256) h[j] = 0;
    __syncthreads();
    const int Etot = Eg + Ed;
    const int base = blockIdx.x * 4096;
    #pragma unroll
    for (int k = 0; k < 16; ++k) {
        int i = base + k * 256 + t;
        if (i < Etot) {
            int b = (i < Eg) ? (dstg[i] >> BSHIFT) : NBg + (dstd[i - Eg] >> BSHIFT);
            atomicAdd(&h[b], 1);
        }
    }
    __syncthreads();
    for (int j = t; j < NBtot; j += 256) {
        int c = h[j];
        if (c) atomicAdd(&bucketCnt[j], c);
    }
}

__global__ void bucket_scan(const int* __restrict__ bucketCnt, int NBtot, int Etot,
                            int* __restrict__ bucketBase, int* __restrict__ bucketCursor)
{
    __shared__ int s[1024];
    int t = threadIdx.x;
    int v = (t < NBtot) ? bucketCnt[t] : 0;
    s[t] = v;
    __syncthreads();
    for (int o = 1; o < 1024; o <<= 1) {
        int add = (t >= o) ? s[t - o] : 0;
        __syncthreads();
        s[t] += add;
        __syncthreads();
    }
    if (t < NBtot) {
        int e = s[t] - v;
        bucketBase[t] = e;
        bucketCursor[t] = e;
    }
    if (t == 0) bucketBase[NBtot] = Etot;
}

__global__ __launch_bounds__(256) void bucket_scatter(
    const int* __restrict__ dstg, const int* __restrict__ srcg, int Eg,
    const int* __restrict__ dstd, const int* __restrict__ srcd, int Ed,
    int NBg, int NBtot, int* __restrict__ bucketCursor, unsigned* __restrict__ coarse)
{
    __shared__ int h[800];
    __shared__ int basearr[800];
    __shared__ int cur[800];
    const int t = threadIdx.x;
    for (int j = t; j < NBtot; j += 256) h[j] = 0;
    __syncthreads();
    const int Etot = Eg + Ed;
    const int base = blockIdx.x * 4096;
    int bk[16];
    unsigned pk[16];
    #pragma unroll
    for (int k = 0; k < 16; ++k) {
        int i = base + k * 256 + t;
        bk[k] = -1;
        if (i < Etot) {
            int dst, src, goff;
            if (i < Eg) { dst = dstg[i]; src = srcg[i]; goff = 0; }
            else        { dst = dstd[i - Eg]; src = srcd[i - Eg]; goff = NBg; }
            bk[k] = goff + (dst >> BSHIFT);
            pk[k] = (unsigned)src | ((unsigned)(dst & 255) << 24);
            atomicAdd(&h[bk[k]], 1);
        }
    }
    __syncthreads();
    for (int j = t; j < NBtot; j += 256) {
        int c = h[j];
        basearr[j] = c ? atomicAdd(&bucketCursor[j], c) : 0;
        cur[j] = 0;
    }
    __syncthreads();
    #pragma unroll
    for (int k = 0; k < 16; ++k) {
        if (bk[k] >= 0) {
            int r = atomicAdd(&cur[bk[k]], 1);
            coarse[basearr[bk[k]] + r] = pk[k];
        }
    }
}

__global__ __launch_bounds__(256) void bucket_sort(
    const unsigned* __restrict__ coarse, const int* __restrict__ bucketBase,
    int NBg, int Eg, int Ed, int N,
    int* __restrict__ offg, int* __restrict__ offd,
    int* __restrict__ srcs_g, int* __restrict__ srcs_d)
{
    __shared__ int hist[256];
    __shared__ int excl[256];
    __shared__ int cur[256];
    const int b = blockIdx.x;
    const int t = threadIdx.x;
    const int s0 = bucketBase[b], s1 = bucketBase[b + 1];
    const int cnt = s1 - s0;
    const bool isg = b < NBg;
    const int d0 = (isg ? b : b - NBg) << BSHIFT;
    hist[t] = 0;
    __syncthreads();
    for (int i = t; i < cnt; i += 256) {
        unsigned p = coarse[s0 + i];
        atomicAdd(&hist[p >> 24], 1);
    }
    __syncthreads();
    int v = hist[t];
    excl[t] = v;
    __syncthreads();
    for (int o = 1; o < 256; o <<= 1) {
        int add = (t >= o) ? excl[t - o] : 0;
        __syncthreads();
        excl[t] += add;
        __syncthreads();
    }
    const int e = excl[t] - v;  // exclusive prefix within bucket
    const int localBase = isg ? s0 : s0 - Eg;
    const int d = d0 + t;
    if (d < N) {
        if (isg) offg[d] = localBase + e;
        else     offd[d] = localBase + e;
    }
    cur[t] = e;
    __syncthreads();
    int* outp = isg ? srcs_g : srcs_d;
    for (int i = t; i < cnt; i += 256) {
        unsigned p = coarse[s0 + i];
        int r = atomicAdd(&cur[p >> 24], 1);
        outp[localBase + r] = (int)(p & 0xFFFFFFu);
    }
    if (b == 0 && t == 0) { offg[N] = Eg; offd[N] = Ed; }
}

// ---------------- per-dst-node softmax aggregation (1 wave per node) ----------------
__global__ __launch_bounds__(256) void aggregate_kernel(
    const float* __restrict__ xs,        // [Ns,128] projected src feats
    const float* __restrict__ esrc,      // [Ns,8]
    const float* __restrict__ edst,      // [Nd,8]
    const int* __restrict__ off,         // [Nd+1]
    const int* __restrict__ srcsorted,   // [E] src ids bucketed by dst
    float* __restrict__ outp,            // [Nd,128]
    int Nd)
{
    __shared__ float exbuf[4][64 * 8];
    const int lane = threadIdx.x & 63;
    const int wslot = threadIdx.x >> 6;
    const int n = blockIdx.x * 4 + wslot;
    if (n >= Nd) return;
    const int o0 = off[n], o1 = off[n + 1];
    const int deg = o1 - o0;
    const int li = lane & 31, half = lane >> 5;
    const int j0 = li * 4;       // this lane's 4 cols (within its half)
    const int hh = li >> 2;      // head owning those cols
    if (deg == 0) {
        if (half == 0) *(float4*)(outp + (size_t)n * 128 + j0) = make_float4(0.f, 0.f, 0.f, 0.f);
        return;
    }
    float ed[8];
    {
        float4 a = *(const float4*)(edst + (size_t)n * 8);
        float4 b = *(const float4*)(edst + (size_t)n * 8 + 4);
        ed[0] = a.x; ed[1] = a.y; ed[2] = a.z; ed[3] = a.w;
        ed[4] = b.x; ed[5] = b.y; ed[6] = b.z; ed[7] = b.w;
    }
    if (deg <= 64) {
        const bool act = lane < deg;
        int s = act ? srcsorted[o0 + lane] : 0;   // coalesced
        float m[8];
        {
            float4 ea = make_float4(0.f, 0.f, 0.f, 0.f), eb = ea;
            if (act) {
                ea = *(const float4*)(esrc + (size_t)s * 8);
                eb = *(const float4*)(esrc + (size_t)s * 8 + 4);
            }
            float a[8] = {ea.x, ea.y, ea.z, ea.w, eb.x, eb.y, eb.z, eb.w};
            #pragma unroll
            for (int h2 = 0; h2 < 8; ++h2) m[h2] = act ? leakyf(a[h2] + ed[h2]) : -1e30f;
        }
        float al[8];
        #pragma unroll
        for (int h2 = 0; h2 < 8; ++h2) al[h2] = m[h2];
        for (int o = 1; o < deg; o <<= 1) {
            #pragma unroll
            for (int h2 = 0; h2 < 8; ++h2) m[h2] = fmaxf(m[h2], __shfl_xor(m[h2], o));
        }
        float exv[8];
        #pragma unroll
        for (int h2 = 0; h2 < 8; ++h2) exv[h2] = act ? __expf(al[h2] - m[h2]) : 0.f;
        *(float4*)(&exbuf[wslot][lane * 8])     = make_float4(exv[0], exv[1], exv[2], exv[3]);
        *(float4*)(&exbuf[wslot][lane * 8 + 4]) = make_float4(exv[4], exv[5], exv[6], exv[7]);
        float4 num = make_float4(0.f, 0.f, 0.f, 0.f);
        float den = 0.f;
        const int iters = (deg + 1) >> 1;
        #pragma unroll 2
        for (int k = 0; k < iters; ++k) {
            int i = 2 * k + half;
            if (i < deg) {
                int si = __shfl(s, i);
                float wgt = exbuf[wslot][i * 8 + hh];
                float4 xv = *(const float4*)(xs + (size_t)si * 128 + j0);
                num.x = fmaf(wgt, xv.x, num.x);
                num.y = fmaf(wgt, xv.y, num.y);
                num.z = fmaf(wgt, xv.z, num.z);
                num.w = fmaf(wgt, xv.w, num.w);
                den += wgt;
            }
        }
        num.x += __shfl_xor(num.x, 32);
        num.y += __shfl_xor(num.y, 32);
        num.z += __shfl_xor(num.z, 32);
        num.w += __shfl_xor(num.w, 32);
        den += __shfl_xor(den, 32);
        if (half == 0) {
            float inv = 1.f / (den + 1e-16f);
            float4 r;
            r.x = fmaxf(num.x * inv, 0.f);
            r.y = fmaxf(num.y * inv, 0.f);
            r.z = fmaxf(num.z * inv, 0.f);
            r.w = fmaxf(num.w * inv, 0.f);
            *(float4*)(outp + (size_t)n * 128 + j0) = r;
        }
        return;
    }
    // ---- slow path (deg > 64) ----
    {
        const int j0b = lane * 2;
        const int h = lane >> 3;
        float m[8];
        #pragma unroll
        for (int hh2 = 0; hh2 < 8; ++hh2) m[hh2] = -1e30f;
        for (int base = 0; base < deg; base += 64) {
            int ii = base + lane;
            bool act = ii < deg;
            int s = srcsorted[o0 + (act ? ii : 0)];
            float4 ea = *(const float4*)(esrc + (size_t)s * 8);
            float4 eb = *(const float4*)(esrc + (size_t)s * 8 + 4);
            float a[8] = {ea.x, ea.y, ea.z, ea.w, eb.x, eb.y, eb.z, eb.w};
            #pragma unroll
            for (int hh2 = 0; hh2 < 8; ++hh2) {
                float v = act ? leakyf(a[hh2] + ed[hh2]) : -1e30f;
                #pragma unroll
                for (int o = 1; o < 64; o <<= 1) v = fmaxf(v, __shfl_xor(v, o));
                m[hh2] = fmaxf(m[hh2], v);
            }
        }
        float mh, edh;
        {
            float t4a = (h & 4) ? m[4] : m[0];
            float t4b = (h & 4) ? m[5] : m[1];
            float t4c = (h & 4) ? m[6] : m[2];
            float t4d = (h & 4) ? m[7] : m[3];
            float t2a = (h & 2) ? t4c : t4a;
            float t2b = (h & 2) ? t4d : t4b;
            mh = (h & 1) ? t2b : t2a;
            float u4a = (h & 4) ? ed[4] : ed[0];
            float u4b = (h & 4) ? ed[5] : ed[1];
            float u4c = (h & 4) ? ed[6] : ed[2];
            float u4d = (h & 4) ? ed[7] : ed[3];
            float u2a = (h & 2) ? u4c : u4a;
            float u2b = (h & 2) ? u4d : u4b;
            edh = (h & 1) ? u2b : u2a;
        }
        float den = 0.f, num0 = 0.f, num1 = 0.f;
        for (int base = 0; base < deg; base += 64) {
            int ii = base + lane;
            bool act = ii < deg;
            int sreg = srcsorted[o0 + (act ? ii : 0)];
            int cl = deg - base;
            if (cl > 64) cl = 64;
            for (int i = 0; i < cl; ++i) {
                int s = __shfl(sreg, i);
                float ev = esrc[(size_t)s * 8 + h];
                float ex = __expf(leakyf(ev + edh) - mh);
                float2 xv = *(const float2*)(xs + (size_t)s * 128 + j0b);
                num0 = fmaf(ex, xv.x, num0);
                num1 = fmaf(ex, xv.y, num1);
                den += ex;
            }
        }
        float inv = 1.f / (den + 1e-16f);
        float r0 = num0 * inv, r1 = num1 * inv;
        r0 = r0 > 0.f ? r0 : 0.f;
        r1 = r1 > 0.f ? r1 : 0.f;
        *(float2*)(outp + (size_t)n * 128 + j0b) = make_float2(r0, r1);
    }
}

// ---------------- fused semantic attention scores for BOTH metapaths ----------------
// Half-tile packing (16 gg rows + 16 dg rows per 32x128 tile); Wk staged in LDS by
// 16-row K-chunks (8 KB) -> LDS 24.6 KB -> 6 blocks/CU (was 4 at 33 KB, occ 37%).
__global__ __launch_bounds__(256) void score2_kernel(
    const float* __restrict__ gg, const float* __restrict__ dg,
    const float* __restrict__ Wk, const float* __restrict__ bk, const float* __restrict__ q,
    float* __restrict__ scoreAcc, int N)
{
    __shared__ float tile[32 * 128];
    __shared__ float wlds[16 * 128];
    __shared__ float sred[8];
    const int t = threadIdx.x;
    const int row0 = blockIdx.x * 16;
    #pragma unroll
    for (int p = 0; p < 4; ++p) {
        int idx = t + 256 * p;
        int r = idx >> 5;
        int c4 = idx & 31;
        int gr = row0 + (r & 15);
        const float* srcp = (r < 16) ? gg : dg;
        float4 v = make_float4(0.f, 0.f, 0.f, 0.f);
        if (gr < N) v = *(const float4*)(srcp + (size_t)gr * 128 + c4 * 4);
        *(float4*)(tile + r * 128 + c4 * 4) = v;
    }
    const int rg = t >> 5, ct = t & 31;
    float acc[4][4];
    {
        float4 bv = *(const float4*)(bk + ct * 4);
        #pragma unroll
        for (int rr = 0; rr < 4; ++rr) {
            acc[rr][0] = bv.x; acc[rr][1] = bv.y; acc[rr][2] = bv.z; acc[rr][3] = bv.w;
        }
    }
    for (int kc = 0; kc < 8; ++kc) {
        __syncthreads();
        #pragma unroll
        for (int p = 0; p < 2; ++p) {
            int idx = t + 256 * p;
            *(float4*)(wlds + idx * 4) = *(const float4*)(Wk + (size_t)kc * 2048 + idx * 4);
        }
        __syncthreads();
        #pragma unroll 2
        for (int i2 = 0; i2 < 16; i2 += 4) {
            const int i = kc * 16 + i2;
            float4 xv[4];
            #pragma unroll
            for (int rr = 0; rr < 4; ++rr) xv[rr] = *(const float4*)(tile + (rg + 8 * rr) * 128 + i);
            #pragma unroll
            for (int qq = 0; qq < 4; ++qq) {
                float4 wv = *(const float4*)(wlds + (i2 + qq) * 128 + ct * 4);
                #pragma unroll
                for (int rr = 0; rr < 4; ++rr) {
                    float xs = ((const float*)&xv[rr])[qq];
                    acc[rr][0] = fmaf(xs, wv.x, acc[rr][0]);
                    acc[rr][1] = fmaf(xs, wv.y, acc[rr][1]);
                    acc[rr][2] = fmaf(xs, wv.z, acc[rr][2]);
                    acc[rr][3] = fmaf(xs, wv.w, acc[rr][3]);
                }
            }
        }
    }
    float4 qv = *(const float4*)(q + ct * 4);
    float pg = 0.f, pd = 0.f;
    #pragma unroll
    for (int rr = 0; rr < 4; ++rr) {
        int r = rg + 8 * rr;               // tile row
        int grow = row0 + (r & 15);        // global row
        if (grow < N) {
            float p_ = 0.f;
            p_ = fmaf(fast_tanh(acc[rr][0]), qv.x, p_);
            p_ = fmaf(fast_tanh(acc[rr][1]), qv.y, p_);
            p_ = fmaf(fast_tanh(acc[rr][2]), qv.z, p_);
            p_ = fmaf(fast_tanh(acc[rr][3]), qv.w, p_);
            if (r < 16) pg += p_; else pd += p_;
        }
    }
    #pragma unroll
    for (int o = 1; o < 64; o <<= 1) {
        pg += __shfl_xor(pg, o);
        pd += __shfl_xor(pd, o);
    }
    if ((t & 63) == 0) {
        sred[(t >> 6) * 2] = pg;
        sred[(t >> 6) * 2 + 1] = pd;
    }
    __syncthreads();
    if (t == 0) {
        float sg = sred[0] + sred[2] + sred[4] + sred[6];
        float sd = sred[1] + sred[3] + sred[5] + sred[7];
        int slot = blockIdx.x & 63;
        atomicAdd(&scoreAcc[slot], sg);
        atomicAdd(&scoreAcc[64 + slot], sd);
    }
}

// ---------------- tiny: reduce 2x64 score slots -> softmax betas ----------------
__global__ void beta_kernel(float* __restrict__ scoreAcc, float invN) {
    int t = threadIdx.x;  // 64 threads
    float v0 = scoreAcc[t];
    float v1 = scoreAcc[64 + t];
    #pragma unroll
    for (int o = 1; o < 64; o <<= 1) {
        v0 += __shfl_xor(v0, o);
        v1 += __shfl_xor(v1, o);
    }
    if (t == 0) {
        float s0 = v0 * invN, s1 = v1 * invN;
        float mx = fmaxf(s0, s1);
        float e0 = __expf(s0 - mx), e1 = __expf(s1 - mx);
        float inv = 1.f / (e0 + e1);
        scoreAcc[128] = e0 * inv;
        scoreAcc[129] = e1 * inv;
    }
}

// ---------------- final: beta blend + @W_lin + b_lin (W_lin staged in LDS) ----------------
__global__ __launch_bounds__(256) void final_kernel(
    const float* __restrict__ gg, const float* __restrict__ dg,
    const float* __restrict__ beta,   // scoreAcc+128: {beta0, beta1}
    const float* __restrict__ Wl, const float* __restrict__ bl,
    float* __restrict__ outp, int N)
{
    __shared__ float wlds[128 * 64];  // 32 KB — whole W_lin
    __shared__ float glds[32 * 128];  // 16 KB — blended tile
    const int t = threadIdx.x;
    #pragma unroll
    for (int p = 0; p < 8; ++p) {
        int idx = (t + 256 * p) * 4;
        *(float4*)(wlds + idx) = *(const float4*)(Wl + idx);
    }
    const float bet0 = beta[0], bet1 = beta[1];
    const int row0 = blockIdx.x * 32;
    #pragma unroll
    for (int p = 0; p < 4; ++p) {
        int idx = t + 256 * p;
        int r = idx >> 5;
        int c4 = idx & 31;
        float4 a = make_float4(0.f, 0.f, 0.f, 0.f), b = a, g;
        if (row0 + r < N) {
            a = *(const float4*)(gg + (size_t)(row0 + r) * 128 + c4 * 4);
            b = *(const float4*)(dg + (size_t)(row0 + r) * 128 + c4 * 4);
        }
        g.x = bet0 * a.x + bet1 * b.x;
        g.y = bet0 * a.y + bet1 * b.y;
        g.z = bet0 * a.z + bet1 * b.z;
        g.w = bet0 * a.w + bet1 * b.w;
        *(float4*)(glds + r * 128 + c4 * 4) = g;
    }
    __syncthreads();
    const int rg = t >> 5, ct = t & 31;
    float acc[4][2];
    {
        float2 bv = *(const float2*)(bl + ct * 2);
        #pragma unroll
        for (int rr = 0; rr < 4; ++rr) { acc[rr][0] = bv.x; acc[rr][1] = bv.y; }
    }
    #pragma unroll 2
    for (int i = 0; i < 128; i += 4) {
        float4 xv[4];
        #pragma unroll
        for (int rr = 0; rr < 4; ++rr) xv[rr] = *(const float4*)(glds + (rg + 8 * rr) * 128 + i);
        #pragma unroll
        for (int qq = 0; qq < 4; ++qq) {
            float2 wv = *(const float2*)(wlds + (i + qq) * 64 + ct * 2);
            #pragma unroll
            for (int rr = 0; rr < 4; ++rr) {
                float xs = ((const float*)&xv[rr])[qq];
                acc[rr][0] = fmaf(xs, wv.x, acc[rr][0]);
                acc[rr][1] = fmaf(xs, wv.y, acc[rr][1]);
            }
        }
    }
    #pragma unroll
    for (int rr = 0; rr < 4; ++rr) {
        int grow = row0 + rg + 8 * rr;
        if (grow < N)
            *(float2*)(outp + (size_t)grow * 64 + ct * 2) = make_float2(acc[rr][0], acc[rr][1]);
    }
}

extern "C" void kernel_launch(void* const* d_in, const int* in_sizes, int n_in,
                              void* d_out, int out_size, void* d_ws, size_t ws_size,
                              hipStream_t stream) {
    (void)n_in; (void)out_size; (void)ws_size;
    const float* x_gene = (const float*)d_in[0];
    const float* x_dis  = (const float*)d_in[1];
    const int* eg_src   = (const int*)d_in[2];
    const int* eg_dst   = (const int*)d_in[3];
    const int* edg_src  = (const int*)d_in[4];
    const int* edg_dst  = (const int*)d_in[5];
    const float* W_gene = (const float*)d_in[6];
    const float* b_gene = (const float*)d_in[7];
    const float* W_dis  = (const float*)d_in[8];
    const float* b_dis  = (const float*)d_in[9];
    const float* att_src_gg = (const float*)d_in[10];
    const float* att_dst_gg = (const float*)d_in[11];
    const float* att_src_dg = (const float*)d_in[12];
    const float* att_dst_dg = (const float*)d_in[13];
    const float* Wk    = (const float*)d_in[14];
    const float* bk    = (const float*)d_in[15];
    const float* q     = (const float*)d_in[16];
    const float* W_lin = (const float*)d_in[17];
    const float* b_lin = (const float*)d_in[18];
    float* out = (float*)d_out;

    const int NG_ = in_sizes[0] / 128;
    const int ND_ = in_sizes[1] / 128;
    const int EG_ = in_sizes[2];
    const int EDG_ = in_sizes[4];

    char* w = (char*)d_ws;
    auto alloc = [&](size_t bytes) -> char* {
        char* p = w;
        w += (bytes + 255) & ~(size_t)255;
        return p;
    };
    float* hg       = (float*)alloc((size_t)NG_ * 128 * 4);
    float* hd       = (float*)alloc((size_t)ND_ * 128 * 4);
    float* e_src_gg = (float*)alloc((size_t)NG_ * 8 * 4);
    float* e_dst_gg = (float*)alloc((size_t)NG_ * 8 * 4);
    float* e_dst_dg = (float*)alloc((size_t)NG_ * 8 * 4);
    float* e_src_dg = (float*)alloc((size_t)ND_ * 8 * 4);
    float* out_gg   = (float*)alloc((size_t)NG_ * 128 * 4);
    int* offg  = (int*)alloc((size_t)(NG_ + 1) * 4);
    int* offd  = (int*)alloc((size_t)(NG_ + 1) * 4);
    int* srcs_g = (int*)alloc((size_t)EG_ * 4);
    int* srcs_d = (int*)alloc((size_t)EDG_ * 4);
    unsigned* coarse = (unsigned*)alloc((size_t)(EG_ + EDG_) * 4);
    int* bucketCnt    = (int*)alloc(4096);
    int* bucketBase   = (int*)alloc(4096);
    int* bucketCursor = (int*)alloc(4096);
    float* score = (float*)alloc(1024);
    float* out_dg = hg;  // hg is dead after the gg aggregation; alias to save 51 MB

    const int NBg = (NG_ + 255) >> BSHIFT;   // 391 for NG=100000
    const int NBtot = 2 * NBg;               // 782 <= 1024 (single-block scan) and <= 800 (LDS arrays)
    const int Etot = EG_ + EDG_;
    const int nbE = (Etot + 4095) / 4096;

    // 1. projections (+ e-vectors)
    proj_kernel<<<(NG_ + 31) / 32, 256, 0, stream>>>(
        x_gene, W_gene, b_gene, hg, NG_,
        att_src_gg, e_src_gg, att_dst_gg, e_dst_gg, att_dst_dg, e_dst_dg);
    proj_kernel<<<(ND_ + 31) / 32, 256, 0, stream>>>(
        x_dis, W_dis, b_dis, hd, ND_,
        att_src_dg, e_src_dg, (const float*)nullptr, (float*)nullptr,
        (const float*)nullptr, (float*)nullptr);

    // 2. two-level bucket CSR build (both graphs)
    hipMemsetAsync(bucketCnt, 0, (size_t)NBtot * 4, stream);
    bucket_hist<<<nbE, 256, 0, stream>>>(eg_dst, EG_, edg_dst, EDG_, NBg, NBtot, bucketCnt);
    bucket_scan<<<1, 1024, 0, stream>>>(bucketCnt, NBtot, Etot, bucketBase, bucketCursor);
    bucket_scatter<<<nbE, 256, 0, stream>>>(
        eg_dst, eg_src, EG_, edg_dst, edg_src, EDG_, NBg, NBtot, bucketCursor, coarse);
    bucket_sort<<<NBtot, 256, 0, stream>>>(
        coarse, bucketBase, NBg, EG_, EDG_, NG_, offg, offd, srcs_g, srcs_d);

    // 3. aggregates (sequential: out_dg aliases hg, which gg-aggregate reads)
    aggregate_kernel<<<(NG_ + 3) / 4, 256, 0, stream>>>(
        hg, e_src_gg, e_dst_gg, offg, srcs_g, out_gg, NG_);
    aggregate_kernel<<<(NG_ + 3) / 4, 256, 0, stream>>>(
        hd, e_src_dg, e_dst_dg, offd, srcs_d, out_dg, NG_);

    // 4. fused semantic attention scores (both metapaths, one pass) + beta
    hipMemsetAsync(score, 0, 512, stream);
    score2_kernel<<<(NG_ + 15) / 16, 256, 0, stream>>>(out_gg, out_dg, Wk, bk, q, score, NG_);
    beta_kernel<<<1, 64, 0, stream>>>(score, 1.0f / (float)NG_);

    // 5. blend + final linear
    final_kernel<<<(NG_ + 31) / 32, 256, 0, stream>>>(
        out_gg, out_dg, score + 128, W_lin, b_lin, out, NG_);
}